// Round 3
// baseline (378.172 us; speedup 1.0000x reference)
//
#include <hip/hip_runtime.h>
#include <cstdint>

typedef __attribute__((ext_vector_type(8))) __bf16 bf16_8;
typedef __attribute__((ext_vector_type(4))) __bf16 bf16_4;
typedef __attribute__((ext_vector_type(4))) float f32x4;

// softmax scale folded into Q:  exp(s/32) = exp2(s * log2(e)/32)
#define QSCALE 0.045084220027780106f

// ---------------------------------------------------------------------------
// async global->LDS, 16B per lane. LDS dest = wave-uniform base + lane*16.
// ---------------------------------------------------------------------------
__device__ __forceinline__ void gld_lds16(const __bf16* g, __bf16* l) {
  __builtin_amdgcn_global_load_lds(
      (const __attribute__((address_space(1))) void*)(void*)g,
      (__attribute__((address_space(3))) void*)l, 16, 0, 0);
}

// ---------------------------------------------------------------------------
// Fused weight transpose + f32->bf16 convert.  W[K][N] -> Wt[N][K] bf16.
// ---------------------------------------------------------------------------
__global__ __launch_bounds__(256) void convt_k(
    const float* __restrict__ Wq, const float* __restrict__ Wk,
    const float* __restrict__ Wv, const float* __restrict__ Wp,
    const float* __restrict__ W1, const float* __restrict__ W2,
    __bf16* __restrict__ WqT, __bf16* __restrict__ WkT,
    __bf16* __restrict__ WvT, __bf16* __restrict__ WpT,
    __bf16* __restrict__ W1T, __bf16* __restrict__ W2T) {
  int bid = blockIdx.x;
  const float* in; __bf16* outp; int Kd, Nd, tile;
  if (bid < 4096) {
    int m = bid >> 10; tile = bid & 1023; Kd = 1024; Nd = 1024;
    in   = m == 0 ? Wq  : m == 1 ? Wk  : m == 2 ? Wv  : Wp;
    outp = m == 0 ? WqT : m == 1 ? WkT : m == 2 ? WvT : WpT;
  } else if (bid < 8192) {
    tile = bid - 4096; Kd = 1024; Nd = 4096; in = W1; outp = W1T;
  } else {
    tile = bid - 8192; Kd = 4096; Nd = 1024; in = W2; outp = W2T;
  }
  int tilesN = Nd >> 5;
  int tk = tile / tilesN, tn = tile % tilesN;
  int k0 = tk * 32, n0 = tn * 32;
  __shared__ float tbuf[32][33];
  int tx = threadIdx.x & 31, ty = threadIdx.x >> 5;  // ty 0..7
#pragma unroll
  for (int i = 0; i < 4; ++i)
    tbuf[ty + i * 8][tx] = in[(size_t)(k0 + ty + i * 8) * Nd + (n0 + tx)];
  __syncthreads();
#pragma unroll
  for (int i = 0; i < 4; ++i)
    outp[(size_t)(n0 + ty + i * 8) * Kd + (k0 + tx)] = (__bf16)tbuf[tx][ty + i * 8];
}

// ---------------------------------------------------------------------------
// LayerNorm over rows of 1024, fp32 in -> bf16 out.  One block per row.
// ---------------------------------------------------------------------------
__global__ __launch_bounds__(256) void ln_k(const float* __restrict__ x,
                                            const float* __restrict__ w,
                                            const float* __restrict__ b,
                                            __bf16* __restrict__ out) {
  int row = blockIdx.x;
  int tid = threadIdx.x;
  f32x4 v = *(const f32x4*)(x + (size_t)row * 1024 + tid * 4);
  float s = v[0] + v[1] + v[2] + v[3];
  float sq = v[0] * v[0] + v[1] * v[1] + v[2] * v[2] + v[3] * v[3];
#pragma unroll
  for (int m = 1; m < 64; m <<= 1) { s += __shfl_xor(s, m); sq += __shfl_xor(sq, m); }
  __shared__ float rs[4], rq[4];
  int wave = tid >> 6, lane = tid & 63;
  if (lane == 0) { rs[wave] = s; rq[wave] = sq; }
  __syncthreads();
  s  = rs[0] + rs[1] + rs[2] + rs[3];
  sq = rq[0] + rq[1] + rq[2] + rq[3];
  float mu   = s * (1.f / 1024.f);
  float var  = sq * (1.f / 1024.f) - mu * mu;
  float rstd = rsqrtf(var + 1e-5f);
  f32x4 wv = *(const f32x4*)(w + tid * 4);
  f32x4 bv = *(const f32x4*)(b + tid * 4);
  bf16_4 o;
#pragma unroll
  for (int i = 0; i < 4; ++i) o[i] = (__bf16)((v[i] - mu) * rstd * wv[i] + bv[i]);
  *(bf16_4*)(out + (size_t)row * 1024 + tid * 4) = o;
}

// ---------------------------------------------------------------------------
// bf16 GEMM: C[M][N] = A[M][K] @ Bt^T, Bt[N][K].  Tile BM x BN x BK, 4 waves
// in 2x2.  Double-buffered LDS, single barrier per K-iter, XOR chunk swizzle
// (global-address side).  (round-5 verified)
// MODE 0: QKV fused via blockIdx.y; chunk 0 (Q) scaled by QSCALE, chunk 1 (K)
//         row-major bf16, chunk 2 writes V^T [(b*16+h)*64+d][2048 tokens]
// MODE 1: bf16 out, +bias, ReLU
// MODE 2: f32  out, +bias, +f32 residual
// ---------------------------------------------------------------------------
template <int MODE, int BM, int BN, int BK>
__global__ __launch_bounds__(256) void gemm_k(
    const __bf16* __restrict__ A,
    const __bf16* __restrict__ B0, const __bf16* __restrict__ B1,
    const __bf16* __restrict__ B2,
    __bf16* __restrict__ O0, __bf16* __restrict__ O1, __bf16* __restrict__ O2,
    float* __restrict__ Of,
    const float* __restrict__ bias, const float* __restrict__ res,
    int K, int Nchunk, int nBlkM, int nBlkN) {
  constexpr int NC = BK / 8;          // 16B chunks per LDS row
  constexpr int MT = BM / 32, NT = BN / 32;
  constexpr int KK = BK / 32;
  constexpr int RPC = 64 / NC;        // rows covered by one gld_lds16 call
  constexpr int CA = BM / RPC / 4;    // A-calls per wave
  constexpr int CB = BN / RPC / 4;    // B-calls per wave
  __shared__ __align__(16) __bf16 As[2][BM * BK];
  __shared__ __align__(16) __bf16 Bs[2][BN * BK];
  int chunk = blockIdx.y;
  const __bf16* Bt = chunk == 0 ? B0 : (chunk == 1 ? B1 : B2);
  __bf16* Ob       = chunk == 0 ? O0 : (chunk == 1 ? O1 : O2);
  int pid = blockIdx.x;
  const int GM = 8;
  int perG = GM * nBlkN;
  int gid = pid / perG;
  int fm = gid * GM;
  int gsz = min(nBlkM - fm, GM);
  int bm = fm + (pid % gsz);
  int bn = (pid % perG) / gsz;
  int m0 = bm * BM, n0 = bn * BN;
  int tid = threadIdx.x, wave = tid >> 6, lane = tid & 63;
  int quad = lane >> 4, l16 = lane & 15;
  int wm = (wave & 1) * (BM / 2), wn = (wave >> 1) * (BN / 2);
  int srow = lane / NC, schunk = lane % NC;

  f32x4 z = {0.f, 0.f, 0.f, 0.f};
  f32x4 acc[MT][NT];
#pragma unroll
  for (int mt = 0; mt < MT; ++mt)
#pragma unroll
    for (int nt = 0; nt < NT; ++nt) acc[mt][nt] = z;

  const __bf16* Ag = A  + (size_t)m0 * K;
  const __bf16* Bg = Bt + (size_t)n0 * K;

  auto stage = [&](int k0, int buf) {
#pragma unroll
    for (int i = 0; i < CA; ++i) {
      int r0 = (wave * CA + i) * RPC;
      int gc = schunk ^ ((r0 + srow) & (NC - 1));
      gld_lds16(Ag + (size_t)(r0 + srow) * K + k0 + gc * 8, &As[buf][r0 * BK]);
    }
#pragma unroll
    for (int i = 0; i < CB; ++i) {
      int r0 = (wave * CB + i) * RPC;
      int gc = schunk ^ ((r0 + srow) & (NC - 1));
      gld_lds16(Bg + (size_t)(r0 + srow) * K + k0 + gc * 8, &Bs[buf][r0 * BK]);
    }
  };

  auto compute = [&](int buf) {
#pragma unroll
    for (int kk = 0; kk < KK; ++kk) {
      bf16_8 af[MT], bfr[NT];
#pragma unroll
      for (int t = 0; t < MT; ++t) {
        int r = wm + t * 16 + l16;
        int lc = (kk * 4 + quad) ^ (r & (NC - 1));
        af[t] = *(const bf16_8*)(&As[buf][r * BK + lc * 8]);
      }
#pragma unroll
      for (int t = 0; t < NT; ++t) {
        int r = wn + t * 16 + l16;
        int lc = (kk * 4 + quad) ^ (r & (NC - 1));
        bfr[t] = *(const bf16_8*)(&Bs[buf][r * BK + lc * 8]);
      }
#pragma unroll
      for (int mt = 0; mt < MT; ++mt)
#pragma unroll
        for (int nt = 0; nt < NT; ++nt)
          acc[mt][nt] = __builtin_amdgcn_mfma_f32_16x16x32_bf16(af[mt], bfr[nt],
                                                                acc[mt][nt], 0, 0, 0);
    }
  };

  int niter = K / BK;
  stage(0, 0);
  __syncthreads();
  for (int it = 0; it < niter - 1; ++it) {
    stage((it + 1) * BK, (it + 1) & 1);  // async prefetch, overlaps compute
    compute(it & 1);
    __syncthreads();                     // drains prefetch + fences buf reuse
  }
  compute((niter - 1) & 1);

  if (MODE == 0 && chunk == 2) {
#pragma unroll
    for (int mt = 0; mt < MT; ++mt) {
      int mbase = m0 + wm + mt * 16 + quad * 4;
      int bb = mbase >> 11, tt = mbase & 2047;
#pragma unroll
      for (int nt = 0; nt < NT; ++nt) {
        int n = n0 + wn + nt * 16 + l16;
        bf16_4 pk;
#pragma unroll
        for (int r = 0; r < 4; ++r) pk[r] = (__bf16)acc[mt][nt][r];
        *(bf16_4*)(O2 + ((size_t)((bb * 16 + (n >> 6)) * 64 + (n & 63))) * 2048 + tt) = pk;
      }
    }
    return;
  }

  float oscale = (MODE == 0 && chunk == 0) ? QSCALE : 1.0f;
#pragma unroll
  for (int mt = 0; mt < MT; ++mt) {
#pragma unroll
    for (int r = 0; r < 4; ++r) {
      int m = m0 + wm + mt * 16 + quad * 4 + r;
      size_t rowo = (size_t)m * Nchunk;
#pragma unroll
      for (int nt = 0; nt < NT; ++nt) {
        int n = n0 + wn + nt * 16 + l16;
        float v = acc[mt][nt][r];
        if (MODE == 0) {
          Ob[rowo + n] = (__bf16)(v * oscale);
        } else if (MODE == 1) {
          v += bias[n]; v = v > 0.f ? v : 0.f;
          Ob[rowo + n] = (__bf16)v;
        } else {
          v += bias[n] + res[rowo + n];
          Of[rowo + n] = v;
        }
      }
    }
  }
}

// ---------------------------------------------------------------------------
// Flash attention, causal, S^T/O^T, fixed-max softmax.
// Round-8: balanced 4-way kv-split (round-7, verified) with the spill fixed.
//   Round-7 post-mortem: __launch_bounds__(256,4) capped VGPRs at 128 < the
//   ~160 live set -> compiler spilled loop state to scratch (VGPR_Count 64,
//   +20 MB HBM scratch traffic, VALUBusy 17.8%).  This round:
//   - __launch_bounds__(256,3): ~170-VGPR cap fits the live set, 3 waves/SIMD
//     (12 waves/CU, 3 blocks/CU, LDS 3x29.7=89 KB ok).
//   - loadV moved AFTER QK^T: V-wait lands at PV, covered by softmax +
//     P-roundtrip + co-resident waves; trims peak live set during QK.
//   - next-K prefetch guarded (no redundant reload on last iter).
//   Work split (verified round-7): pair (j,63-j) = 33 tiles flattened,
//   split {9,8,8,8} over 4 waves; partials summed via LDS (fixed-max softmax
//   makes combine a pure sum), one __syncthreads, owners finalize.
// ---------------------------------------------------------------------------
__global__ __launch_bounds__(256, 3) void attn_k(const __bf16* __restrict__ Q,
                                                 const __bf16* __restrict__ K,
                                                 const __bf16* __restrict__ Vt,
                                                 __bf16* __restrict__ O) {
  __shared__ __align__(16) __bf16 Pls[4][32 * 72];  // P roundtrip; [1],[2] reused as hi-partials
  __shared__ __align__(16) __bf16 Xbuf[2][32 * 72]; // [0]: w0-hi partial, [1]: w1-lo partial
  __shared__ float Lbuf[4][32][4];                  // partial l: 0:w0-hi 1:w1-lo 2:w1-hi 3:w2-hi

  int i = blockIdx.x;
  int bh = i & 31, j = i >> 5;          // j = pair index 0..31
  int h = bh & 15, b = bh >> 4;
  int tid = threadIdx.x, wave = tid >> 6, lane = tid & 63;
  int quad = lane >> 4, l16 = lane & 15;
  int qg_lo = j, qg_hi = 63 - j;
  int t_lo = (j >> 1) + 1;              // 1..16 (t_hi = 33 - t_lo)
  int u0 = wave == 0 ? 0 : wave == 1 ? 9 : wave == 2 ? 17 : 25;
  int u1 = wave == 0 ? 9 : wave == 1 ? 17 : wave == 2 ? 25 : 33;
  int lo0 = u0, lo1 = min(u1, t_lo);             // lo segment (maybe empty)
  int hi0 = max(u0, t_lo) - t_lo, hi1 = u1 - t_lo;  // hi segment (maybe empty)

  const __bf16* Kb = K + (size_t)(b * 2048) * 1024 + h * 64;
  const __bf16* Vh = Vt + (size_t)((b * 16 + h) * 64) * 2048;
  __bf16* Pw = &Pls[wave][0];

  f32x4 z = {0.f, 0.f, 0.f, 0.f};
  bf16_8 qf[2][2], kfr[4][2], vfr[4][2];
  f32x4 ot[2][4];
  float l_acc[2];

  auto loadK = [&](int kt) {
#pragma unroll
    for (int kk = 0; kk < 4; ++kk) {
      const __bf16* kr = Kb + (size_t)(kt + kk * 16 + l16) * 1024 + quad * 8;
      kfr[kk][0] = *(const bf16_8*)(kr);
      kfr[kk][1] = *(const bf16_8*)(kr + 32);
    }
  };
  auto loadV = [&](int kt) {
#pragma unroll
    for (int dt = 0; dt < 4; ++dt) {
      const __bf16* vr = Vh + (size_t)(dt * 16 + l16) * 2048 + kt + quad * 8;
      vfr[dt][0] = *(const bf16_8*)(vr);
      vfr[dt][1] = *(const bf16_8*)(vr + 32);
    }
  };

  // process tiles [it0, it1) of q-group qg; leaves result in ot/l_acc
  auto run = [&](int qg, int it0, int it1) {
#pragma unroll
    for (int g = 0; g < 2; ++g) {
      const __bf16* Qg = Q + ((size_t)(b * 2048 + qg * 32 + g * 16 + l16)) * 1024 + h * 64;
      qf[g][0] = *(const bf16_8*)(Qg + quad * 8);
      qf[g][1] = *(const bf16_8*)(Qg + 32 + quad * 8);
    }
#pragma unroll
    for (int g = 0; g < 2; ++g) {
#pragma unroll
      for (int dt = 0; dt < 4; ++dt) ot[g][dt] = z;
      l_acc[g] = 0.f;
    }
    if (it0 >= it1) return;
    int qw = qg * 32;
    loadK(it0 * 64);                     // K prologue (register-pipelined)
    for (int it = it0; it < it1; ++it) {
      int kt = it * 64;
      bool masked = (kt + 63 > qw);
      // --- S^T = K.Q^T, both q-groups share K fragments ---
      f32x4 sf[2][4];
#pragma unroll
      for (int kk = 0; kk < 4; ++kk) {
#pragma unroll
        for (int g = 0; g < 2; ++g) {
          f32x4 a = z;
          a = __builtin_amdgcn_mfma_f32_16x16x32_bf16(kfr[kk][0], qf[g][0], a, 0, 0, 0);
          a = __builtin_amdgcn_mfma_f32_16x16x32_bf16(kfr[kk][1], qf[g][1], a, 0, 0, 0);
          sf[g][kk] = a;
        }
      }
      if (it + 1 < it1) loadK((it + 1) * 64);  // prefetch next K (WAR after QK)
      loadV(kt);                               // V-wait lands at PV, after softmax
      // --- softmax (fixed max), P -> per-wave LDS ---
#pragma unroll
      for (int g = 0; g < 2; ++g) {
        int qrow = qw + g * 16 + l16;
#pragma unroll
        for (int kk = 0; kk < 4; ++kk) {
          bf16_4 pk;
#pragma unroll
          for (int r = 0; r < 4; ++r) {
            float x = sf[g][kk][r];
            if (masked && (kt + kk * 16 + quad * 4 + r > qrow)) x = -1e30f;
            float pp = __builtin_amdgcn_exp2f(x);
            l_acc[g] += pp;
            pk[r] = (__bf16)pp;
          }
          *(bf16_4*)(Pw + (g * 16 + l16) * 72 + kk * 16 + quad * 4) = pk;
        }
      }
      bf16_8 pf[2][2];
#pragma unroll
      for (int g = 0; g < 2; ++g) {
        pf[g][0] = *(const bf16_8*)(Pw + (g * 16 + l16) * 72 + quad * 8);
        pf[g][1] = *(const bf16_8*)(Pw + (g * 16 + l16) * 72 + 32 + quad * 8);
      }
      // --- O^T += V^T.P^T, both q-groups share V fragments ---
#pragma unroll
      for (int dt = 0; dt < 4; ++dt) {
#pragma unroll
        for (int g = 0; g < 2; ++g) {
          ot[g][dt] = __builtin_amdgcn_mfma_f32_16x16x32_bf16(vfr[dt][0], pf[g][0], ot[g][dt], 0, 0, 0);
          ot[g][dt] = __builtin_amdgcn_mfma_f32_16x16x32_bf16(vfr[dt][1], pf[g][1], ot[g][dt], 0, 0, 0);
        }
      }
    }
  };

  auto putP = [&](__bf16* Ob, float (*Lb)[4]) {
#pragma unroll
    for (int g = 0; g < 2; ++g) {
#pragma unroll
      for (int dt = 0; dt < 4; ++dt) {
        bf16_4 pk;
#pragma unroll
        for (int r = 0; r < 4; ++r) pk[r] = (__bf16)ot[g][dt][r];
        *(bf16_4*)(Ob + (g * 16 + l16) * 72 + dt * 16 + quad * 4) = pk;
      }
      Lb[g * 16 + l16][quad] = l_acc[g];
    }
  };
  auto addP = [&](const __bf16* Ob, const float (*Lb)[4]) {
#pragma unroll
    for (int g = 0; g < 2; ++g) {
#pragma unroll
      for (int dt = 0; dt < 4; ++dt) {
        bf16_4 pk = *(const bf16_4*)(Ob + (g * 16 + l16) * 72 + dt * 16 + quad * 4);
#pragma unroll
        for (int r = 0; r < 4; ++r) ot[g][dt][r] += (float)pk[r];
      }
      l_acc[g] += Lb[g * 16 + l16][quad];
    }
  };
  auto writeO = [&](int qg) {
#pragma unroll
    for (int g = 0; g < 2; ++g) {
      float l = l_acc[g];
      l += __shfl_xor(l, 16);
      l += __shfl_xor(l, 32);
      float inv = 1.0f / l;
      size_t base = (size_t)(b * 2048 + qg * 32 + g * 16 + l16) * 1024 + h * 64;
#pragma unroll
      for (int dt = 0; dt < 4; ++dt) {
        bf16_4 ok;
#pragma unroll
        for (int r = 0; r < 4; ++r) ok[r] = (__bf16)(ot[g][dt][r] * inv);
        *(bf16_4*)(O + base + dt * 16 + quad * 4) = ok;
      }
    }
  };

  if (wave == 0) {
    run(qg_hi, hi0, hi1);                 // hi head (maybe empty)
    putP(&Xbuf[0][0], Lbuf[0]);
    run(qg_lo, lo0, lo1);                 // lo head (always non-empty)
    __syncthreads();
    addP(&Xbuf[1][0], Lbuf[1]);           // w1's lo tail (zeros if none)
    writeO(qg_lo);
  } else if (wave == 1) {
    run(qg_lo, lo0, lo1);                 // lo tail (maybe empty)
    putP(&Xbuf[1][0], Lbuf[1]);
    run(qg_hi, hi0, hi1);                 // hi mid (always non-empty)
    putP(&Pls[1][0], Lbuf[2]);            // own P buffer, done with P
    __syncthreads();
  } else if (wave == 2) {
    run(qg_hi, hi0, hi1);
    putP(&Pls[2][0], Lbuf[3]);
    __syncthreads();
  } else {
    run(qg_hi, hi0, hi1);                 // hi tail (owner)
    __syncthreads();
    addP(&Pls[1][0], Lbuf[2]);
    addP(&Pls[2][0], Lbuf[3]);
    addP(&Xbuf[0][0], Lbuf[0]);
    writeO(qg_hi);
  }
}

// ---------------------------------------------------------------------------
extern "C" void kernel_launch(void* const* d_in, const int* in_sizes, int n_in,
                              void* d_out, int out_size, void* d_ws,
                              size_t ws_size, hipStream_t stream) {
  const float* x   = (const float*)d_in[0];
  const float* Wq  = (const float*)d_in[1];
  const float* Wk  = (const float*)d_in[2];
  const float* Wv  = (const float*)d_in[3];
  const float* Wp  = (const float*)d_in[4];
  const float* bp  = (const float*)d_in[5];
  const float* W1  = (const float*)d_in[6];
  const float* b1  = (const float*)d_in[7];
  const float* W2  = (const float*)d_in[8];
  const float* b2  = (const float*)d_in[9];
  const float* l1w = (const float*)d_in[10];
  const float* l1b = (const float*)d_in[11];
  const float* l2w = (const float*)d_in[12];
  const float* l2b = (const float*)d_in[13];
  float* out = (float*)d_out;
  char* ws = (char*)d_ws;
  const size_t MB = 1024ull * 1024ull;
  __bf16* WqT = (__bf16*)(ws + 0 * MB);   // 2 MB  [1024][1024]
  __bf16* WkT = (__bf16*)(ws + 2 * MB);   // 2 MB
  __bf16* WvT = (__bf16*)(ws + 4 * MB);   // 2 MB
  __bf16* WpT = (__bf16*)(ws + 6 * MB);   // 2 MB
  __bf16* W1T = (__bf16*)(ws + 8 * MB);   // 8 MB  [4096][1024]
  __bf16* W2T = (__bf16*)(ws + 16 * MB);  // 8 MB  [1024][4096]
  __bf16* hb  = (__bf16*)(ws + 24 * MB);  // 8 MB  LN out (reused for LN2)
  __bf16* Qb  = (__bf16*)(ws + 32 * MB);  // 8 MB  Q (pre-scaled by QSCALE)
  __bf16* Kb_ = (__bf16*)(ws + 40 * MB);  // 8 MB
  __bf16* Vt  = (__bf16*)(ws + 48 * MB);  // 8 MB  V^T [b*16+h][64][2048]
  __bf16* Ab  = (__bf16*)(ws + 56 * MB);  // 8 MB  attention out
  __bf16* F1  = (__bf16*)(ws + 64 * MB);  // 32 MB FFN hidden

  convt_k<<<12288, 256, 0, stream>>>(Wq, Wk, Wv, Wp, W1, W2,
                                     WqT, WkT, WvT, WpT, W1T, W2T);
  ln_k<<<4096, 256, 0, stream>>>(x, l1w, l1b, hb);
  // fused QKV (chunk 0 = Q scaled, chunk 2 writes V^T per head)
  gemm_k<0, 128, 128, 32><<<dim3(256, 3), 256, 0, stream>>>(
      hb, WqT, WkT, WvT, Qb, Kb_, Vt, nullptr, nullptr, nullptr,
      1024, 1024, 32, 8);
  attn_k<<<1024, 256, 0, stream>>>(Qb, Kb_, Vt, Ab);
  // x1 = x + attn @ Wproj + bproj (fp32, into d_out); 64x64x64 tiles, 4 blk/CU
  gemm_k<2, 64, 64, 64><<<dim3(1024, 1), 256, 0, stream>>>(
      Ab, WpT, WpT, WpT, nullptr, nullptr, nullptr, out, bp, x,
      1024, 1024, 64, 16);
  ln_k<<<4096, 256, 0, stream>>>(out, l2w, l2b, hb);
  // ff1 = relu(h2 @ W1 + b1)
  gemm_k<1, 128, 128, 32><<<dim3(1024, 1), 256, 0, stream>>>(
      hb, W1T, W1T, W1T, F1, F1, F1, nullptr, b1, nullptr,
      1024, 4096, 32, 32);
  // out = x1 + ff1 @ W2 + b2 ; 64x64x64 tiles, 4 blk/CU
  gemm_k<2, 64, 64, 64><<<dim3(1024, 1), 256, 0, stream>>>(
      F1, W2T, W2T, W2T, nullptr, nullptr, nullptr, out, b2, out,
      4096, 1024, 64, 16);
}

// Round 4
// 346.524 us; speedup vs baseline: 1.0913x; 1.0913x over previous
//
#include <hip/hip_runtime.h>
#include <cstdint>

typedef __attribute__((ext_vector_type(8))) __bf16 bf16_8;
typedef __attribute__((ext_vector_type(4))) __bf16 bf16_4;
typedef __attribute__((ext_vector_type(4))) float f32x4;

// softmax scale folded into Q:  exp(s/32) = exp2(s * log2(e)/32)
#define QSCALE 0.045084220027780106f

// ---------------------------------------------------------------------------
// async global->LDS, 16B per lane. LDS dest = wave-uniform base + lane*16.
// ---------------------------------------------------------------------------
__device__ __forceinline__ void gld_lds16(const __bf16* g, __bf16* l) {
  __builtin_amdgcn_global_load_lds(
      (const __attribute__((address_space(1))) void*)(void*)g,
      (__attribute__((address_space(3))) void*)l, 16, 0, 0);
}

// ---------------------------------------------------------------------------
// Fused weight transpose + f32->bf16 convert.  W[K][N] -> Wt[N][K] bf16.
// ---------------------------------------------------------------------------
__global__ __launch_bounds__(256) void convt_k(
    const float* __restrict__ Wq, const float* __restrict__ Wk,
    const float* __restrict__ Wv, const float* __restrict__ Wp,
    const float* __restrict__ W1, const float* __restrict__ W2,
    __bf16* __restrict__ WqT, __bf16* __restrict__ WkT,
    __bf16* __restrict__ WvT, __bf16* __restrict__ WpT,
    __bf16* __restrict__ W1T, __bf16* __restrict__ W2T) {
  int bid = blockIdx.x;
  const float* in; __bf16* outp; int Kd, Nd, tile;
  if (bid < 4096) {
    int m = bid >> 10; tile = bid & 1023; Kd = 1024; Nd = 1024;
    in   = m == 0 ? Wq  : m == 1 ? Wk  : m == 2 ? Wv  : Wp;
    outp = m == 0 ? WqT : m == 1 ? WkT : m == 2 ? WvT : WpT;
  } else if (bid < 8192) {
    tile = bid - 4096; Kd = 1024; Nd = 4096; in = W1; outp = W1T;
  } else {
    tile = bid - 8192; Kd = 4096; Nd = 1024; in = W2; outp = W2T;
  }
  int tilesN = Nd >> 5;
  int tk = tile / tilesN, tn = tile % tilesN;
  int k0 = tk * 32, n0 = tn * 32;
  __shared__ float tbuf[32][33];
  int tx = threadIdx.x & 31, ty = threadIdx.x >> 5;  // ty 0..7
#pragma unroll
  for (int i = 0; i < 4; ++i)
    tbuf[ty + i * 8][tx] = in[(size_t)(k0 + ty + i * 8) * Nd + (n0 + tx)];
  __syncthreads();
#pragma unroll
  for (int i = 0; i < 4; ++i)
    outp[(size_t)(n0 + ty + i * 8) * Kd + (k0 + tx)] = (__bf16)tbuf[tx][ty + i * 8];
}

// ---------------------------------------------------------------------------
// LayerNorm over rows of 1024, fp32 in -> bf16 out.  One block per row.
// ---------------------------------------------------------------------------
__global__ __launch_bounds__(256) void ln_k(const float* __restrict__ x,
                                            const float* __restrict__ w,
                                            const float* __restrict__ b,
                                            __bf16* __restrict__ out) {
  int row = blockIdx.x;
  int tid = threadIdx.x;
  f32x4 v = *(const f32x4*)(x + (size_t)row * 1024 + tid * 4);
  float s = v[0] + v[1] + v[2] + v[3];
  float sq = v[0] * v[0] + v[1] * v[1] + v[2] * v[2] + v[3] * v[3];
#pragma unroll
  for (int m = 1; m < 64; m <<= 1) { s += __shfl_xor(s, m); sq += __shfl_xor(sq, m); }
  __shared__ float rs[4], rq[4];
  int wave = tid >> 6, lane = tid & 63;
  if (lane == 0) { rs[wave] = s; rq[wave] = sq; }
  __syncthreads();
  s  = rs[0] + rs[1] + rs[2] + rs[3];
  sq = rq[0] + rq[1] + rq[2] + rq[3];
  float mu   = s * (1.f / 1024.f);
  float var  = sq * (1.f / 1024.f) - mu * mu;
  float rstd = rsqrtf(var + 1e-5f);
  f32x4 wv = *(const f32x4*)(w + tid * 4);
  f32x4 bv = *(const f32x4*)(b + tid * 4);
  bf16_4 o;
#pragma unroll
  for (int i = 0; i < 4; ++i) o[i] = (__bf16)((v[i] - mu) * rstd * wv[i] + bv[i]);
  *(bf16_4*)(out + (size_t)row * 1024 + tid * 4) = o;
}

// ---------------------------------------------------------------------------
// bf16 GEMM: C[M][N] = A[M][K] @ Bt^T, Bt[N][K].  Tile BM x BN x BK, 4 waves
// in 2x2.  Double-buffered LDS, single barrier per K-iter, XOR chunk swizzle
// (global-address side).  (round-5 verified)
// MODE 0: QKV fused via blockIdx.y; chunk 0 (Q) scaled by QSCALE, chunk 1 (K)
//         row-major bf16, chunk 2 writes V^T [(b*16+h)*64+d][2048 tokens]
// MODE 1: bf16 out, +bias, ReLU
// MODE 2: f32  out, +bias, +f32 residual
// ---------------------------------------------------------------------------
template <int MODE, int BM, int BN, int BK>
__global__ __launch_bounds__(256) void gemm_k(
    const __bf16* __restrict__ A,
    const __bf16* __restrict__ B0, const __bf16* __restrict__ B1,
    const __bf16* __restrict__ B2,
    __bf16* __restrict__ O0, __bf16* __restrict__ O1, __bf16* __restrict__ O2,
    float* __restrict__ Of,
    const float* __restrict__ bias, const float* __restrict__ res,
    int K, int Nchunk, int nBlkM, int nBlkN) {
  constexpr int NC = BK / 8;          // 16B chunks per LDS row
  constexpr int MT = BM / 32, NT = BN / 32;
  constexpr int KK = BK / 32;
  constexpr int RPC = 64 / NC;        // rows covered by one gld_lds16 call
  constexpr int CA = BM / RPC / 4;    // A-calls per wave
  constexpr int CB = BN / RPC / 4;    // B-calls per wave
  __shared__ __align__(16) __bf16 As[2][BM * BK];
  __shared__ __align__(16) __bf16 Bs[2][BN * BK];
  int chunk = blockIdx.y;
  const __bf16* Bt = chunk == 0 ? B0 : (chunk == 1 ? B1 : B2);
  __bf16* Ob       = chunk == 0 ? O0 : (chunk == 1 ? O1 : O2);
  int pid = blockIdx.x;
  const int GM = 8;
  int perG = GM * nBlkN;
  int gid = pid / perG;
  int fm = gid * GM;
  int gsz = min(nBlkM - fm, GM);
  int bm = fm + (pid % gsz);
  int bn = (pid % perG) / gsz;
  int m0 = bm * BM, n0 = bn * BN;
  int tid = threadIdx.x, wave = tid >> 6, lane = tid & 63;
  int quad = lane >> 4, l16 = lane & 15;
  int wm = (wave & 1) * (BM / 2), wn = (wave >> 1) * (BN / 2);
  int srow = lane / NC, schunk = lane % NC;

  f32x4 z = {0.f, 0.f, 0.f, 0.f};
  f32x4 acc[MT][NT];
#pragma unroll
  for (int mt = 0; mt < MT; ++mt)
#pragma unroll
    for (int nt = 0; nt < NT; ++nt) acc[mt][nt] = z;

  const __bf16* Ag = A  + (size_t)m0 * K;
  const __bf16* Bg = Bt + (size_t)n0 * K;

  auto stage = [&](int k0, int buf) {
#pragma unroll
    for (int i = 0; i < CA; ++i) {
      int r0 = (wave * CA + i) * RPC;
      int gc = schunk ^ ((r0 + srow) & (NC - 1));
      gld_lds16(Ag + (size_t)(r0 + srow) * K + k0 + gc * 8, &As[buf][r0 * BK]);
    }
#pragma unroll
    for (int i = 0; i < CB; ++i) {
      int r0 = (wave * CB + i) * RPC;
      int gc = schunk ^ ((r0 + srow) & (NC - 1));
      gld_lds16(Bg + (size_t)(r0 + srow) * K + k0 + gc * 8, &Bs[buf][r0 * BK]);
    }
  };

  auto compute = [&](int buf) {
#pragma unroll
    for (int kk = 0; kk < KK; ++kk) {
      bf16_8 af[MT], bfr[NT];
#pragma unroll
      for (int t = 0; t < MT; ++t) {
        int r = wm + t * 16 + l16;
        int lc = (kk * 4 + quad) ^ (r & (NC - 1));
        af[t] = *(const bf16_8*)(&As[buf][r * BK + lc * 8]);
      }
#pragma unroll
      for (int t = 0; t < NT; ++t) {
        int r = wn + t * 16 + l16;
        int lc = (kk * 4 + quad) ^ (r & (NC - 1));
        bfr[t] = *(const bf16_8*)(&Bs[buf][r * BK + lc * 8]);
      }
#pragma unroll
      for (int mt = 0; mt < MT; ++mt)
#pragma unroll
        for (int nt = 0; nt < NT; ++nt)
          acc[mt][nt] = __builtin_amdgcn_mfma_f32_16x16x32_bf16(af[mt], bfr[nt],
                                                                acc[mt][nt], 0, 0, 0);
    }
  };

  int niter = K / BK;
  stage(0, 0);
  __syncthreads();
  for (int it = 0; it < niter - 1; ++it) {
    stage((it + 1) * BK, (it + 1) & 1);  // async prefetch, overlaps compute
    compute(it & 1);
    __syncthreads();                     // drains prefetch + fences buf reuse
  }
  compute((niter - 1) & 1);

  if (MODE == 0 && chunk == 2) {
#pragma unroll
    for (int mt = 0; mt < MT; ++mt) {
      int mbase = m0 + wm + mt * 16 + quad * 4;
      int bb = mbase >> 11, tt = mbase & 2047;
#pragma unroll
      for (int nt = 0; nt < NT; ++nt) {
        int n = n0 + wn + nt * 16 + l16;
        bf16_4 pk;
#pragma unroll
        for (int r = 0; r < 4; ++r) pk[r] = (__bf16)acc[mt][nt][r];
        *(bf16_4*)(O2 + ((size_t)((bb * 16 + (n >> 6)) * 64 + (n & 63))) * 2048 + tt) = pk;
      }
    }
    return;
  }

  float oscale = (MODE == 0 && chunk == 0) ? QSCALE : 1.0f;
#pragma unroll
  for (int mt = 0; mt < MT; ++mt) {
#pragma unroll
    for (int r = 0; r < 4; ++r) {
      int m = m0 + wm + mt * 16 + quad * 4 + r;
      size_t rowo = (size_t)m * Nchunk;
#pragma unroll
      for (int nt = 0; nt < NT; ++nt) {
        int n = n0 + wn + nt * 16 + l16;
        float v = acc[mt][nt][r];
        if (MODE == 0) {
          Ob[rowo + n] = (__bf16)(v * oscale);
        } else if (MODE == 1) {
          v += bias[n]; v = v > 0.f ? v : 0.f;
          Ob[rowo + n] = (__bf16)v;
        } else {
          v += bias[n] + res[rowo + n];
          Of[rowo + n] = v;
        }
      }
    }
  }
}

// ---------------------------------------------------------------------------
// Flash attention, causal, S^T/O^T, fixed-max softmax.
// Round-9: register diet so 4 waves/SIMD fits WITHOUT spill.
//   Rounds 7/8 post-mortem: true live set ~200 VGPR (kfr32+vfr32+sf32+qf16+
//   ot32+pf16+addr) -> every cap <200 spilled to scratch (WRITE_SIZE 21-29MB
//   vs 8.2 real).  This round sheds ~80 regs STRUCTURALLY:
//   - softmax fused into the QK loop per-16-col chunk (fixed-max softmax has
//     no row reduction): sf 32 -> 8 live.
//   - K and V time-share ONE register block kv[4][2] (K for QK, overwritten
//     by V for PV; WAR within the tile): 64 -> 32.
//   - PV done in two half-K passes re-reading P from LDS: pf 16 -> 8.
//   Peak ~120 < 128 -> __launch_bounds__(256,4), grid 1024 = exactly
//   4 blocks/CU, no tail, no spill.  V latency is covered by the P-LDS
//   roundtrip + 4-way wave TLP (un-spilled for the first time).
//   Work split (verified round-7): pair (j,63-j) = 33 tiles flattened, split
//   {9,8,8,8} over 4 waves; partials summed via LDS (fixed-max softmax makes
//   combine a pure sum), one __syncthreads, owners finalize.
// ---------------------------------------------------------------------------
__global__ __launch_bounds__(256, 4) void attn_k(const __bf16* __restrict__ Q,
                                                 const __bf16* __restrict__ K,
                                                 const __bf16* __restrict__ Vt,
                                                 __bf16* __restrict__ O) {
  __shared__ __align__(16) __bf16 Pls[4][32 * 72];  // P roundtrip; [1],[2] reused as hi-partials
  __shared__ __align__(16) __bf16 Xbuf[2][32 * 72]; // [0]: w0-hi partial, [1]: w1-lo partial
  __shared__ float Lbuf[4][32][4];                  // partial l: 0:w0-hi 1:w1-lo 2:w1-hi 3:w2-hi

  int i = blockIdx.x;
  int bh = i & 31, j = i >> 5;          // j = pair index 0..31
  int h = bh & 15, b = bh >> 4;
  int tid = threadIdx.x, wave = tid >> 6, lane = tid & 63;
  int quad = lane >> 4, l16 = lane & 15;
  int qg_lo = j, qg_hi = 63 - j;
  int t_lo = (j >> 1) + 1;              // 1..16 (t_hi = 33 - t_lo)
  int u0 = wave == 0 ? 0 : wave == 1 ? 9 : wave == 2 ? 17 : 25;
  int u1 = wave == 0 ? 9 : wave == 1 ? 17 : wave == 2 ? 25 : 33;
  int lo0 = u0, lo1 = min(u1, t_lo);             // lo segment (maybe empty)
  int hi0 = max(u0, t_lo) - t_lo, hi1 = u1 - t_lo;  // hi segment (maybe empty)

  const __bf16* Kb = K + (size_t)(b * 2048) * 1024 + h * 64;
  const __bf16* Vh = Vt + (size_t)((b * 16 + h) * 64) * 2048;
  __bf16* Pw = &Pls[wave][0];

  f32x4 z = {0.f, 0.f, 0.f, 0.f};
  bf16_8 qf[2][2], kv[4][2];            // kv: K during QK, V during PV (WAR)
  f32x4 ot[2][4];
  float l_acc[2];

  auto loadK = [&](int kt) {
#pragma unroll
    for (int kk = 0; kk < 4; ++kk) {
      const __bf16* kr = Kb + (size_t)(kt + kk * 16 + l16) * 1024 + quad * 8;
      kv[kk][0] = *(const bf16_8*)(kr);
      kv[kk][1] = *(const bf16_8*)(kr + 32);
    }
  };
  auto loadV = [&](int kt) {
#pragma unroll
    for (int dt = 0; dt < 4; ++dt) {
      const __bf16* vr = Vh + (size_t)(dt * 16 + l16) * 2048 + kt + quad * 8;
      kv[dt][0] = *(const bf16_8*)(vr);
      kv[dt][1] = *(const bf16_8*)(vr + 32);
    }
  };

  // process tiles [it0, it1) of q-group qg; leaves result in ot/l_acc
  auto run = [&](int qg, int it0, int it1) {
#pragma unroll
    for (int g = 0; g < 2; ++g) {
      const __bf16* Qg = Q + ((size_t)(b * 2048 + qg * 32 + g * 16 + l16)) * 1024 + h * 64;
      qf[g][0] = *(const bf16_8*)(Qg + quad * 8);
      qf[g][1] = *(const bf16_8*)(Qg + 32 + quad * 8);
    }
#pragma unroll
    for (int g = 0; g < 2; ++g) {
#pragma unroll
      for (int dt = 0; dt < 4; ++dt) ot[g][dt] = z;
      l_acc[g] = 0.f;
    }
    if (it0 >= it1) return;
    int qw = qg * 32;
    loadK(it0 * 64);
    for (int it = it0; it < it1; ++it) {
      int kt = it * 64;
      bool masked = (kt + 63 > qw);
      // --- QK^T + fused softmax per 16-col chunk (sf never fully live) ---
#pragma unroll
      for (int kk = 0; kk < 4; ++kk) {
        f32x4 s[2];
#pragma unroll
        for (int g = 0; g < 2; ++g) {
          f32x4 a = z;
          a = __builtin_amdgcn_mfma_f32_16x16x32_bf16(kv[kk][0], qf[g][0], a, 0, 0, 0);
          a = __builtin_amdgcn_mfma_f32_16x16x32_bf16(kv[kk][1], qf[g][1], a, 0, 0, 0);
          s[g] = a;
        }
#pragma unroll
        for (int g = 0; g < 2; ++g) {
          int qrow = qw + g * 16 + l16;
          bf16_4 pk;
#pragma unroll
          for (int r = 0; r < 4; ++r) {
            float x = s[g][r];
            if (masked && (kt + kk * 16 + quad * 4 + r > qrow)) x = -1e30f;
            float pp = __builtin_amdgcn_exp2f(x);
            l_acc[g] += pp;
            pk[r] = (__bf16)pp;
          }
          *(bf16_4*)(Pw + (g * 16 + l16) * 72 + kk * 16 + quad * 4) = pk;
        }
      }
      loadV(kt);                         // overwrites kv (WAR after QK)
      // --- O^T += V^T.P^T in two half-K passes (pf 8 regs live) ---
#pragma unroll
      for (int hf = 0; hf < 2; ++hf) {
        bf16_8 pf0 = *(const bf16_8*)(Pw + (l16) * 72 + hf * 32 + quad * 8);
        bf16_8 pf1 = *(const bf16_8*)(Pw + (16 + l16) * 72 + hf * 32 + quad * 8);
#pragma unroll
        for (int dt = 0; dt < 4; ++dt) {
          ot[0][dt] = __builtin_amdgcn_mfma_f32_16x16x32_bf16(kv[dt][hf], pf0, ot[0][dt], 0, 0, 0);
          ot[1][dt] = __builtin_amdgcn_mfma_f32_16x16x32_bf16(kv[dt][hf], pf1, ot[1][dt], 0, 0, 0);
        }
      }
      if (it + 1 < it1) loadK((it + 1) * 64);  // overwrites kv (WAR after PV)
    }
  };

  auto putP = [&](__bf16* Ob, float (*Lb)[4]) {
#pragma unroll
    for (int g = 0; g < 2; ++g) {
#pragma unroll
      for (int dt = 0; dt < 4; ++dt) {
        bf16_4 pk;
#pragma unroll
        for (int r = 0; r < 4; ++r) pk[r] = (__bf16)ot[g][dt][r];
        *(bf16_4*)(Ob + (g * 16 + l16) * 72 + dt * 16 + quad * 4) = pk;
      }
      Lb[g * 16 + l16][quad] = l_acc[g];
    }
  };
  auto addP = [&](const __bf16* Ob, const float (*Lb)[4]) {
#pragma unroll
    for (int g = 0; g < 2; ++g) {
#pragma unroll
      for (int dt = 0; dt < 4; ++dt) {
        bf16_4 pk = *(const bf16_4*)(Ob + (g * 16 + l16) * 72 + dt * 16 + quad * 4);
#pragma unroll
        for (int r = 0; r < 4; ++r) ot[g][dt][r] += (float)pk[r];
      }
      l_acc[g] += Lb[g * 16 + l16][quad];
    }
  };
  auto writeO = [&](int qg) {
#pragma unroll
    for (int g = 0; g < 2; ++g) {
      float l = l_acc[g];
      l += __shfl_xor(l, 16);
      l += __shfl_xor(l, 32);
      float inv = 1.0f / l;
      size_t base = (size_t)(b * 2048 + qg * 32 + g * 16 + l16) * 1024 + h * 64;
#pragma unroll
      for (int dt = 0; dt < 4; ++dt) {
        bf16_4 ok;
#pragma unroll
        for (int r = 0; r < 4; ++r) ok[r] = (__bf16)(ot[g][dt][r] * inv);
        *(bf16_4*)(O + base + dt * 16 + quad * 4) = ok;
      }
    }
  };

  if (wave == 0) {
    run(qg_hi, hi0, hi1);                 // hi head (maybe empty)
    putP(&Xbuf[0][0], Lbuf[0]);
    run(qg_lo, lo0, lo1);                 // lo head (always non-empty)
    __syncthreads();
    addP(&Xbuf[1][0], Lbuf[1]);           // w1's lo tail (zeros if none)
    writeO(qg_lo);
  } else if (wave == 1) {
    run(qg_lo, lo0, lo1);                 // lo tail (maybe empty)
    putP(&Xbuf[1][0], Lbuf[1]);
    run(qg_hi, hi0, hi1);                 // hi mid (always non-empty)
    putP(&Pls[1][0], Lbuf[2]);            // own P buffer, done with P
    __syncthreads();
  } else if (wave == 2) {
    run(qg_hi, hi0, hi1);
    putP(&Pls[2][0], Lbuf[3]);
    __syncthreads();
  } else {
    run(qg_hi, hi0, hi1);                 // hi tail (owner)
    __syncthreads();
    addP(&Pls[1][0], Lbuf[2]);
    addP(&Pls[2][0], Lbuf[3]);
    addP(&Xbuf[0][0], Lbuf[0]);
    writeO(qg_hi);
  }
}

// ---------------------------------------------------------------------------
extern "C" void kernel_launch(void* const* d_in, const int* in_sizes, int n_in,
                              void* d_out, int out_size, void* d_ws,
                              size_t ws_size, hipStream_t stream) {
  const float* x   = (const float*)d_in[0];
  const float* Wq  = (const float*)d_in[1];
  const float* Wk  = (const float*)d_in[2];
  const float* Wv  = (const float*)d_in[3];
  const float* Wp  = (const float*)d_in[4];
  const float* bp  = (const float*)d_in[5];
  const float* W1  = (const float*)d_in[6];
  const float* b1  = (const float*)d_in[7];
  const float* W2  = (const float*)d_in[8];
  const float* b2  = (const float*)d_in[9];
  const float* l1w = (const float*)d_in[10];
  const float* l1b = (const float*)d_in[11];
  const float* l2w = (const float*)d_in[12];
  const float* l2b = (const float*)d_in[13];
  float* out = (float*)d_out;
  char* ws = (char*)d_ws;
  const size_t MB = 1024ull * 1024ull;
  __bf16* WqT = (__bf16*)(ws + 0 * MB);   // 2 MB  [1024][1024]
  __bf16* WkT = (__bf16*)(ws + 2 * MB);   // 2 MB
  __bf16* WvT = (__bf16*)(ws + 4 * MB);   // 2 MB
  __bf16* WpT = (__bf16*)(ws + 6 * MB);   // 2 MB
  __bf16* W1T = (__bf16*)(ws + 8 * MB);   // 8 MB  [4096][1024]
  __bf16* W2T = (__bf16*)(ws + 16 * MB);  // 8 MB  [1024][4096]
  __bf16* hb  = (__bf16*)(ws + 24 * MB);  // 8 MB  LN out (reused for LN2)
  __bf16* Qb  = (__bf16*)(ws + 32 * MB);  // 8 MB  Q (pre-scaled by QSCALE)
  __bf16* Kb_ = (__bf16*)(ws + 40 * MB);  // 8 MB
  __bf16* Vt  = (__bf16*)(ws + 48 * MB);  // 8 MB  V^T [b*16+h][64][2048]
  __bf16* Ab  = (__bf16*)(ws + 56 * MB);  // 8 MB  attention out
  __bf16* F1  = (__bf16*)(ws + 64 * MB);  // 32 MB FFN hidden

  convt_k<<<12288, 256, 0, stream>>>(Wq, Wk, Wv, Wp, W1, W2,
                                     WqT, WkT, WvT, WpT, W1T, W2T);
  ln_k<<<4096, 256, 0, stream>>>(x, l1w, l1b, hb);
  // fused QKV (chunk 0 = Q scaled, chunk 2 writes V^T per head)
  gemm_k<0, 128, 128, 32><<<dim3(256, 3), 256, 0, stream>>>(
      hb, WqT, WkT, WvT, Qb, Kb_, Vt, nullptr, nullptr, nullptr,
      1024, 1024, 32, 8);
  attn_k<<<1024, 256, 0, stream>>>(Qb, Kb_, Vt, Ab);
  // x1 = x + attn @ Wproj + bproj (fp32, into d_out); 64x64x64 tiles, 4 blk/CU
  gemm_k<2, 64, 64, 64><<<dim3(1024, 1), 256, 0, stream>>>(
      Ab, WpT, WpT, WpT, nullptr, nullptr, nullptr, out, bp, x,
      1024, 1024, 64, 16);
  ln_k<<<4096, 256, 0, stream>>>(out, l2w, l2b, hb);
  // ff1 = relu(h2 @ W1 + b1)
  gemm_k<1, 128, 128, 32><<<dim3(1024, 1), 256, 0, stream>>>(
      hb, W1T, W1T, W1T, F1, F1, F1, nullptr, b1, nullptr,
      1024, 4096, 32, 32);
  // out = x1 + ff1 @ W2 + b2 ; 64x64x64 tiles, 4 blk/CU
  gemm_k<2, 64, 64, 64><<<dim3(1024, 1), 256, 0, stream>>>(
      F1, W2T, W2T, W2T, nullptr, nullptr, nullptr, out, b2, out,
      4096, 1024, 64, 16);
}

// Round 5
// 343.253 us; speedup vs baseline: 1.1017x; 1.0095x over previous
//
#include <hip/hip_runtime.h>
#include <cstdint>

typedef __attribute__((ext_vector_type(8))) __bf16 bf16_8;
typedef __attribute__((ext_vector_type(4))) __bf16 bf16_4;
typedef __attribute__((ext_vector_type(4))) float f32x4;

// softmax scale folded into Q:  exp(s/32) = exp2(s * log2(e)/32)
#define QSCALE 0.045084220027780106f

// ---------------------------------------------------------------------------
// async global->LDS, 16B per lane. LDS dest = wave-uniform base + lane*16.
// ---------------------------------------------------------------------------
__device__ __forceinline__ void gld_lds16(const __bf16* g, __bf16* l) {
  __builtin_amdgcn_global_load_lds(
      (const __attribute__((address_space(1))) void*)(void*)g,
      (__attribute__((address_space(3))) void*)l, 16, 0, 0);
}

// ---------------------------------------------------------------------------
// Fused weight transpose + f32->bf16 convert.  W[K][N] -> Wt[N][K] bf16.
// ---------------------------------------------------------------------------
__global__ __launch_bounds__(256) void convt_k(
    const float* __restrict__ Wq, const float* __restrict__ Wk,
    const float* __restrict__ Wv, const float* __restrict__ Wp,
    const float* __restrict__ W1, const float* __restrict__ W2,
    __bf16* __restrict__ WqT, __bf16* __restrict__ WkT,
    __bf16* __restrict__ WvT, __bf16* __restrict__ WpT,
    __bf16* __restrict__ W1T, __bf16* __restrict__ W2T) {
  int bid = blockIdx.x;
  const float* in; __bf16* outp; int Kd, Nd, tile;
  if (bid < 4096) {
    int m = bid >> 10; tile = bid & 1023; Kd = 1024; Nd = 1024;
    in   = m == 0 ? Wq  : m == 1 ? Wk  : m == 2 ? Wv  : Wp;
    outp = m == 0 ? WqT : m == 1 ? WkT : m == 2 ? WvT : WpT;
  } else if (bid < 8192) {
    tile = bid - 4096; Kd = 1024; Nd = 4096; in = W1; outp = W1T;
  } else {
    tile = bid - 8192; Kd = 4096; Nd = 1024; in = W2; outp = W2T;
  }
  int tilesN = Nd >> 5;
  int tk = tile / tilesN, tn = tile % tilesN;
  int k0 = tk * 32, n0 = tn * 32;
  __shared__ float tbuf[32][33];
  int tx = threadIdx.x & 31, ty = threadIdx.x >> 5;  // ty 0..7
#pragma unroll
  for (int i = 0; i < 4; ++i)
    tbuf[ty + i * 8][tx] = in[(size_t)(k0 + ty + i * 8) * Nd + (n0 + tx)];
  __syncthreads();
#pragma unroll
  for (int i = 0; i < 4; ++i)
    outp[(size_t)(n0 + ty + i * 8) * Kd + (k0 + tx)] = (__bf16)tbuf[tx][ty + i * 8];
}

// ---------------------------------------------------------------------------
// LayerNorm over rows of 1024, fp32 in -> bf16 out.  One block per row.
// ---------------------------------------------------------------------------
__global__ __launch_bounds__(256) void ln_k(const float* __restrict__ x,
                                            const float* __restrict__ w,
                                            const float* __restrict__ b,
                                            __bf16* __restrict__ out) {
  int row = blockIdx.x;
  int tid = threadIdx.x;
  f32x4 v = *(const f32x4*)(x + (size_t)row * 1024 + tid * 4);
  float s = v[0] + v[1] + v[2] + v[3];
  float sq = v[0] * v[0] + v[1] * v[1] + v[2] * v[2] + v[3] * v[3];
#pragma unroll
  for (int m = 1; m < 64; m <<= 1) { s += __shfl_xor(s, m); sq += __shfl_xor(sq, m); }
  __shared__ float rs[4], rq[4];
  int wave = tid >> 6, lane = tid & 63;
  if (lane == 0) { rs[wave] = s; rq[wave] = sq; }
  __syncthreads();
  s  = rs[0] + rs[1] + rs[2] + rs[3];
  sq = rq[0] + rq[1] + rq[2] + rq[3];
  float mu   = s * (1.f / 1024.f);
  float var  = sq * (1.f / 1024.f) - mu * mu;
  float rstd = rsqrtf(var + 1e-5f);
  f32x4 wv = *(const f32x4*)(w + tid * 4);
  f32x4 bv = *(const f32x4*)(b + tid * 4);
  bf16_4 o;
#pragma unroll
  for (int i = 0; i < 4; ++i) o[i] = (__bf16)((v[i] - mu) * rstd * wv[i] + bv[i]);
  *(bf16_4*)(out + (size_t)row * 1024 + tid * 4) = o;
}

// ---------------------------------------------------------------------------
// bf16 GEMM: C[M][N] = A[M][K] @ Bt^T, Bt[N][K].  Tile BM x BN x BK, 4 waves
// in 2x2.  Double-buffered LDS, single barrier per K-iter, XOR chunk swizzle
// (global-address side).  (round-5 verified)
// MODE 0: QKV fused via blockIdx.y; chunk 0 (Q) scaled by QSCALE, chunk 1 (K)
//         row-major bf16, chunk 2 writes V^T [(b*16+h)*64+d][2048 tokens]
// MODE 1: bf16 out, +bias, ReLU
// MODE 2: f32  out, +bias, +f32 residual
// ---------------------------------------------------------------------------
template <int MODE, int BM, int BN, int BK>
__global__ __launch_bounds__(256) void gemm_k(
    const __bf16* __restrict__ A,
    const __bf16* __restrict__ B0, const __bf16* __restrict__ B1,
    const __bf16* __restrict__ B2,
    __bf16* __restrict__ O0, __bf16* __restrict__ O1, __bf16* __restrict__ O2,
    float* __restrict__ Of,
    const float* __restrict__ bias, const float* __restrict__ res,
    int K, int Nchunk, int nBlkM, int nBlkN) {
  constexpr int NC = BK / 8;          // 16B chunks per LDS row
  constexpr int MT = BM / 32, NT = BN / 32;
  constexpr int KK = BK / 32;
  constexpr int RPC = 64 / NC;        // rows covered by one gld_lds16 call
  constexpr int CA = BM / RPC / 4;    // A-calls per wave
  constexpr int CB = BN / RPC / 4;    // B-calls per wave
  __shared__ __align__(16) __bf16 As[2][BM * BK];
  __shared__ __align__(16) __bf16 Bs[2][BN * BK];
  int chunk = blockIdx.y;
  const __bf16* Bt = chunk == 0 ? B0 : (chunk == 1 ? B1 : B2);
  __bf16* Ob       = chunk == 0 ? O0 : (chunk == 1 ? O1 : O2);
  int pid = blockIdx.x;
  const int GM = 8;
  int perG = GM * nBlkN;
  int gid = pid / perG;
  int fm = gid * GM;
  int gsz = min(nBlkM - fm, GM);
  int bm = fm + (pid % gsz);
  int bn = (pid % perG) / gsz;
  int m0 = bm * BM, n0 = bn * BN;
  int tid = threadIdx.x, wave = tid >> 6, lane = tid & 63;
  int quad = lane >> 4, l16 = lane & 15;
  int wm = (wave & 1) * (BM / 2), wn = (wave >> 1) * (BN / 2);
  int srow = lane / NC, schunk = lane % NC;

  f32x4 z = {0.f, 0.f, 0.f, 0.f};
  f32x4 acc[MT][NT];
#pragma unroll
  for (int mt = 0; mt < MT; ++mt)
#pragma unroll
    for (int nt = 0; nt < NT; ++nt) acc[mt][nt] = z;

  const __bf16* Ag = A  + (size_t)m0 * K;
  const __bf16* Bg = Bt + (size_t)n0 * K;

  auto stage = [&](int k0, int buf) {
#pragma unroll
    for (int i = 0; i < CA; ++i) {
      int r0 = (wave * CA + i) * RPC;
      int gc = schunk ^ ((r0 + srow) & (NC - 1));
      gld_lds16(Ag + (size_t)(r0 + srow) * K + k0 + gc * 8, &As[buf][r0 * BK]);
    }
#pragma unroll
    for (int i = 0; i < CB; ++i) {
      int r0 = (wave * CB + i) * RPC;
      int gc = schunk ^ ((r0 + srow) & (NC - 1));
      gld_lds16(Bg + (size_t)(r0 + srow) * K + k0 + gc * 8, &Bs[buf][r0 * BK]);
    }
  };

  auto compute = [&](int buf) {
#pragma unroll
    for (int kk = 0; kk < KK; ++kk) {
      bf16_8 af[MT], bfr[NT];
#pragma unroll
      for (int t = 0; t < MT; ++t) {
        int r = wm + t * 16 + l16;
        int lc = (kk * 4 + quad) ^ (r & (NC - 1));
        af[t] = *(const bf16_8*)(&As[buf][r * BK + lc * 8]);
      }
#pragma unroll
      for (int t = 0; t < NT; ++t) {
        int r = wn + t * 16 + l16;
        int lc = (kk * 4 + quad) ^ (r & (NC - 1));
        bfr[t] = *(const bf16_8*)(&Bs[buf][r * BK + lc * 8]);
      }
#pragma unroll
      for (int mt = 0; mt < MT; ++mt)
#pragma unroll
        for (int nt = 0; nt < NT; ++nt)
          acc[mt][nt] = __builtin_amdgcn_mfma_f32_16x16x32_bf16(af[mt], bfr[nt],
                                                                acc[mt][nt], 0, 0, 0);
    }
  };

  int niter = K / BK;
  stage(0, 0);
  __syncthreads();
  for (int it = 0; it < niter - 1; ++it) {
    stage((it + 1) * BK, (it + 1) & 1);  // async prefetch, overlaps compute
    compute(it & 1);
    __syncthreads();                     // drains prefetch + fences buf reuse
  }
  compute((niter - 1) & 1);

  if (MODE == 0 && chunk == 2) {
#pragma unroll
    for (int mt = 0; mt < MT; ++mt) {
      int mbase = m0 + wm + mt * 16 + quad * 4;
      int bb = mbase >> 11, tt = mbase & 2047;
#pragma unroll
      for (int nt = 0; nt < NT; ++nt) {
        int n = n0 + wn + nt * 16 + l16;
        bf16_4 pk;
#pragma unroll
        for (int r = 0; r < 4; ++r) pk[r] = (__bf16)acc[mt][nt][r];
        *(bf16_4*)(O2 + ((size_t)((bb * 16 + (n >> 6)) * 64 + (n & 63))) * 2048 + tt) = pk;
      }
    }
    return;
  }

  float oscale = (MODE == 0 && chunk == 0) ? QSCALE : 1.0f;
#pragma unroll
  for (int mt = 0; mt < MT; ++mt) {
#pragma unroll
    for (int r = 0; r < 4; ++r) {
      int m = m0 + wm + mt * 16 + quad * 4 + r;
      size_t rowo = (size_t)m * Nchunk;
#pragma unroll
      for (int nt = 0; nt < NT; ++nt) {
        int n = n0 + wn + nt * 16 + l16;
        float v = acc[mt][nt][r];
        if (MODE == 0) {
          Ob[rowo + n] = (__bf16)(v * oscale);
        } else if (MODE == 1) {
          v += bias[n]; v = v > 0.f ? v : 0.f;
          Ob[rowo + n] = (__bf16)v;
        } else {
          v += bias[n] + res[rowo + n];
          Of[rowo + n] = v;
        }
      }
    }
  }
}

// ---------------------------------------------------------------------------
// Flash attention, causal, S^T/O^T, fixed-max softmax.
// Round-10: cooperative staged pipeline (round-0 verified compute/stage code)
// + deterministic pair balance (rounds 7-9 verified mapping).
//   Round-4 post-mortem: per-wave direct-global fragment loads are strictly
//   serial per tile (K-wait -> QK -> softmax -> V-wait -> PV); ~2 L2 round
//   trips exposed per tile, 4 waves/SIMD can't cover it (VALUBusy 20%).
//   Round-0's cooperative LDS staging (4 waves share each staged K/V tile,
//   async gld_lds16, prefetch-1-ahead, 1 barrier/tile) had ~1 us/tile; its
//   62 us was tail-CU-bound (dispatch-dependent heavy/light pairing), not
//   per-tile-bound.  Fix the balance AT BLOCK LEVEL instead:
//   - 128-row q-tile pair (qt, 15-qt) stages exactly 2(qt+1)+2(16-qt) = 34
//     kv tiles.  Block = (pair j 0..7, bh 0..31) = 256 blocks = 1/CU exactly,
//     uniform work under ANY dispatch order.
//   - One flat 34-tile double-buffered loop; staging depends only on kt
//     (same b,h for both phases).  At the phase boundary: write O for phase
//     A, reload Q fragments, zero accumulators, keep the pipeline running.
//   - blockIdx&31 = bh -> same-head blocks share an XCD's L2 (K+V 512KB/head,
//     4 heads/XCD = 2MB < 4MB).
//   Per-wave: 32 q-rows as two 16-col groups sharing K/V LDS fragment loads
//   (round-0 layout, verified).  Waves skip fully-masked tiles (stage always).
// ---------------------------------------------------------------------------
__global__ __launch_bounds__(256) void attn_k(const __bf16* __restrict__ Q,
                                              const __bf16* __restrict__ K,
                                              const __bf16* __restrict__ Vt,
                                              __bf16* __restrict__ O) {
  __shared__ __align__(16) __bf16 Kls[2][64 * 64];
  __shared__ __align__(16) __bf16 Vls[2][64 * 64];
  __shared__ __align__(16) __bf16 Pls[4][32 * 72];

  int i = blockIdx.x;
  int bh = i & 31, j = i >> 5;           // j = pair index 0..7
  int h = bh & 15, b = bh >> 4;
  int qtA = 15 - j, qtB = j;             // heavy phase first
  int nA = 2 * (qtA + 1), nB = 2 * (qtB + 1);
  int nT = nA + nB;                      // always 34
  int tid = threadIdx.x, wave = tid >> 6, lane = tid & 63;
  int quad = lane >> 4, l16 = lane & 15;
  int r8 = lane >> 3, c8 = lane & 7;
  int cswz = c8 ^ r8;                    // staging chunk swizzle
  int so0 = (quad ^ (l16 & 7)) * 8;      // frag chunk offset
  int so1 = so0 ^ 32;

  const __bf16* Kb = K + (size_t)(b * 2048) * 1024 + h * 64;
  const __bf16* Vh = Vt + (size_t)((b * 16 + h) * 64) * 2048;
  __bf16* Pw = &Pls[wave][0];

  f32x4 z = {0.f, 0.f, 0.f, 0.f};
  bf16_8 qf[2][2];
  f32x4 ot[2][4];
  float l_acc[2] = {0.f, 0.f};
  int qw = qtA * 128 + wave * 32;        // this wave's rows in current phase

  auto loadQ = [&](int qt) {
    qw = qt * 128 + wave * 32;
#pragma unroll
    for (int g = 0; g < 2; ++g) {
      const __bf16* Qg = Q + ((size_t)(b * 2048 + qw + g * 16 + l16)) * 1024 + h * 64;
      qf[g][0] = *(const bf16_8*)(Qg + quad * 8);
      qf[g][1] = *(const bf16_8*)(Qg + 32 + quad * 8);
    }
#pragma unroll
    for (int g = 0; g < 2; ++g) {
#pragma unroll
      for (int dt = 0; dt < 4; ++dt) ot[g][dt] = z;
      l_acc[g] = 0.f;
    }
  };

  auto stage = [&](int kt, int buf) {
#pragma unroll
    for (int i2 = 0; i2 < 2; ++i2) {
      int rl = wave * 16 + i2 * 8 + r8;
      gld_lds16(Kb + (size_t)(kt + rl) * 1024 + cswz * 8,
                &Kls[buf][(wave * 16 + i2 * 8) * 64]);
      gld_lds16(Vh + (size_t)rl * 2048 + kt + cswz * 8,
                &Vls[buf][(wave * 16 + i2 * 8) * 64]);
    }
  };

  auto writeO = [&]() {
#pragma unroll
    for (int g = 0; g < 2; ++g) {
      float l = l_acc[g];
      l += __shfl_xor(l, 16);
      l += __shfl_xor(l, 32);
      float inv = 1.0f / l;
      size_t base = (size_t)(b * 2048 + qw + g * 16 + l16) * 1024 + h * 64;
#pragma unroll
      for (int dt = 0; dt < 4; ++dt) {
        bf16_4 ok;
#pragma unroll
        for (int r = 0; r < 4; ++r) ok[r] = (__bf16)(ot[g][dt][r] * inv);
        *(bf16_4*)(O + base + dt * 16 + quad * 4) = ok;
      }
    }
  };

  auto ktOf = [&](int t) { return (t < nA ? t : t - nA) * 64; };

  loadQ(qtA);
  stage(0, 0);
  __syncthreads();
  for (int t = 0; t < nT; ++t) {
    int kt = ktOf(t);
    int buf = t & 1;
    if (t + 1 < nT) stage(ktOf(t + 1), buf ^ 1);  // async prefetch
    if (t == nA) {                       // phase boundary (wave-uniform)
      writeO();
      loadQ(qtB);
    }
    if (kt <= qw + 31) {                 // wave-uniform: skip fully-masked
      bool masked = (kt + 63 > qw);
      // --- S^T = K.Q^T, both q-groups share K fragments ---
      f32x4 sf[2][4];
#pragma unroll
      for (int kk = 0; kk < 4; ++kk) {
        const __bf16* kr = &Kls[buf][(kk * 16 + l16) * 64];
        bf16_8 ka = *(const bf16_8*)(kr + so0);
        bf16_8 kb = *(const bf16_8*)(kr + so1);
#pragma unroll
        for (int g = 0; g < 2; ++g) {
          f32x4 a = z;
          a = __builtin_amdgcn_mfma_f32_16x16x32_bf16(ka, qf[g][0], a, 0, 0, 0);
          a = __builtin_amdgcn_mfma_f32_16x16x32_bf16(kb, qf[g][1], a, 0, 0, 0);
          sf[g][kk] = a;
        }
      }
      // --- softmax (fixed max), P -> LDS ---
#pragma unroll
      for (int g = 0; g < 2; ++g) {
        int qrow = qw + g * 16 + l16;
#pragma unroll
        for (int kk = 0; kk < 4; ++kk) {
          bf16_4 pk;
#pragma unroll
          for (int r = 0; r < 4; ++r) {
            float x = sf[g][kk][r];
            if (masked && (kt + kk * 16 + quad * 4 + r > qrow)) x = -1e30f;
            float p = __builtin_amdgcn_exp2f(x);
            l_acc[g] += p;
            pk[r] = (__bf16)p;
          }
          *(bf16_4*)(Pw + (g * 16 + l16) * 72 + kk * 16 + quad * 4) = pk;
        }
      }
      // --- O^T += V^T.P^T, both q-groups share V fragments ---
      bf16_8 pf[2][2];
#pragma unroll
      for (int g = 0; g < 2; ++g) {
        pf[g][0] = *(const bf16_8*)(Pw + (g * 16 + l16) * 72 + quad * 8);
        pf[g][1] = *(const bf16_8*)(Pw + (g * 16 + l16) * 72 + 32 + quad * 8);
      }
#pragma unroll
      for (int dt = 0; dt < 4; ++dt) {
        const __bf16* vr = &Vls[buf][(dt * 16 + l16) * 64];
        bf16_8 v0 = *(const bf16_8*)(vr + so0);
        bf16_8 v1 = *(const bf16_8*)(vr + so1);
#pragma unroll
        for (int g = 0; g < 2; ++g) {
          ot[g][dt] = __builtin_amdgcn_mfma_f32_16x16x32_bf16(v0, pf[g][0], ot[g][dt], 0, 0, 0);
          ot[g][dt] = __builtin_amdgcn_mfma_f32_16x16x32_bf16(v1, pf[g][1], ot[g][dt], 0, 0, 0);
        }
      }
    }
    __syncthreads();                     // drains prefetch + fences buf reuse
  }
  writeO();                              // phase B output
}

// ---------------------------------------------------------------------------
extern "C" void kernel_launch(void* const* d_in, const int* in_sizes, int n_in,
                              void* d_out, int out_size, void* d_ws,
                              size_t ws_size, hipStream_t stream) {
  const float* x   = (const float*)d_in[0];
  const float* Wq  = (const float*)d_in[1];
  const float* Wk  = (const float*)d_in[2];
  const float* Wv  = (const float*)d_in[3];
  const float* Wp  = (const float*)d_in[4];
  const float* bp  = (const float*)d_in[5];
  const float* W1  = (const float*)d_in[6];
  const float* b1  = (const float*)d_in[7];
  const float* W2  = (const float*)d_in[8];
  const float* b2  = (const float*)d_in[9];
  const float* l1w = (const float*)d_in[10];
  const float* l1b = (const float*)d_in[11];
  const float* l2w = (const float*)d_in[12];
  const float* l2b = (const float*)d_in[13];
  float* out = (float*)d_out;
  char* ws = (char*)d_ws;
  const size_t MB = 1024ull * 1024ull;
  __bf16* WqT = (__bf16*)(ws + 0 * MB);   // 2 MB  [1024][1024]
  __bf16* WkT = (__bf16*)(ws + 2 * MB);   // 2 MB
  __bf16* WvT = (__bf16*)(ws + 4 * MB);   // 2 MB
  __bf16* WpT = (__bf16*)(ws + 6 * MB);   // 2 MB
  __bf16* W1T = (__bf16*)(ws + 8 * MB);   // 8 MB  [4096][1024]
  __bf16* W2T = (__bf16*)(ws + 16 * MB);  // 8 MB  [1024][4096]
  __bf16* hb  = (__bf16*)(ws + 24 * MB);  // 8 MB  LN out (reused for LN2)
  __bf16* Qb  = (__bf16*)(ws + 32 * MB);  // 8 MB  Q (pre-scaled by QSCALE)
  __bf16* Kb_ = (__bf16*)(ws + 40 * MB);  // 8 MB
  __bf16* Vt  = (__bf16*)(ws + 48 * MB);  // 8 MB  V^T [b*16+h][64][2048]
  __bf16* Ab  = (__bf16*)(ws + 56 * MB);  // 8 MB  attention out
  __bf16* F1  = (__bf16*)(ws + 64 * MB);  // 32 MB FFN hidden

  convt_k<<<12288, 256, 0, stream>>>(Wq, Wk, Wv, Wp, W1, W2,
                                     WqT, WkT, WvT, WpT, W1T, W2T);
  ln_k<<<4096, 256, 0, stream>>>(x, l1w, l1b, hb);
  // fused QKV (chunk 0 = Q scaled, chunk 2 writes V^T per head)
  gemm_k<0, 128, 128, 32><<<dim3(256, 3), 256, 0, stream>>>(
      hb, WqT, WkT, WvT, Qb, Kb_, Vt, nullptr, nullptr, nullptr,
      1024, 1024, 32, 8);
  attn_k<<<256, 256, 0, stream>>>(Qb, Kb_, Vt, Ab);
  // x1 = x + attn @ Wproj + bproj (fp32, into d_out); 64x64x64 tiles, 4 blk/CU
  gemm_k<2, 64, 64, 64><<<dim3(1024, 1), 256, 0, stream>>>(
      Ab, WpT, WpT, WpT, nullptr, nullptr, nullptr, out, bp, x,
      1024, 1024, 64, 16);
  ln_k<<<4096, 256, 0, stream>>>(out, l2w, l2b, hb);
  // ff1 = relu(h2 @ W1 + b1)
  gemm_k<1, 128, 128, 32><<<dim3(1024, 1), 256, 0, stream>>>(
      hb, W1T, W1T, W1T, F1, F1, F1, nullptr, b1, nullptr,
      1024, 4096, 32, 32);
  // out = x1 + ff1 @ W2 + b2 ; 64x64x64 tiles, 4 blk/CU
  gemm_k<2, 64, 64, 64><<<dim3(1024, 1), 256, 0, stream>>>(
      F1, W2T, W2T, W2T, nullptr, nullptr, nullptr, out, b2, out,
      4096, 1024, 64, 16);
}

// Round 6
// 338.543 us; speedup vs baseline: 1.1171x; 1.0139x over previous
//
#include <hip/hip_runtime.h>
#include <cstdint>

typedef __attribute__((ext_vector_type(8))) __bf16 bf16_8;
typedef __attribute__((ext_vector_type(4))) __bf16 bf16_4;
typedef __attribute__((ext_vector_type(4))) float f32x4;

// softmax scale folded into Q:  exp(s/32) = exp2(s * log2(e)/32)
#define QSCALE 0.045084220027780106f

// ---------------------------------------------------------------------------
// async global->LDS, 16B per lane. LDS dest = wave-uniform base + lane*16.
// ---------------------------------------------------------------------------
__device__ __forceinline__ void gld_lds16(const __bf16* g, __bf16* l) {
  __builtin_amdgcn_global_load_lds(
      (const __attribute__((address_space(1))) void*)(void*)g,
      (__attribute__((address_space(3))) void*)l, 16, 0, 0);
}

// ---------------------------------------------------------------------------
// Fused weight transpose + f32->bf16 convert.  W[K][N] -> Wt[N][K] bf16.
// ---------------------------------------------------------------------------
__global__ __launch_bounds__(256) void convt_k(
    const float* __restrict__ Wq, const float* __restrict__ Wk,
    const float* __restrict__ Wv, const float* __restrict__ Wp,
    const float* __restrict__ W1, const float* __restrict__ W2,
    __bf16* __restrict__ WqT, __bf16* __restrict__ WkT,
    __bf16* __restrict__ WvT, __bf16* __restrict__ WpT,
    __bf16* __restrict__ W1T, __bf16* __restrict__ W2T) {
  int bid = blockIdx.x;
  const float* in; __bf16* outp; int Kd, Nd, tile;
  if (bid < 4096) {
    int m = bid >> 10; tile = bid & 1023; Kd = 1024; Nd = 1024;
    in   = m == 0 ? Wq  : m == 1 ? Wk  : m == 2 ? Wv  : Wp;
    outp = m == 0 ? WqT : m == 1 ? WkT : m == 2 ? WvT : WpT;
  } else if (bid < 8192) {
    tile = bid - 4096; Kd = 1024; Nd = 4096; in = W1; outp = W1T;
  } else {
    tile = bid - 8192; Kd = 4096; Nd = 1024; in = W2; outp = W2T;
  }
  int tilesN = Nd >> 5;
  int tk = tile / tilesN, tn = tile % tilesN;
  int k0 = tk * 32, n0 = tn * 32;
  __shared__ float tbuf[32][33];
  int tx = threadIdx.x & 31, ty = threadIdx.x >> 5;  // ty 0..7
#pragma unroll
  for (int i = 0; i < 4; ++i)
    tbuf[ty + i * 8][tx] = in[(size_t)(k0 + ty + i * 8) * Nd + (n0 + tx)];
  __syncthreads();
#pragma unroll
  for (int i = 0; i < 4; ++i)
    outp[(size_t)(n0 + ty + i * 8) * Kd + (k0 + tx)] = (__bf16)tbuf[tx][ty + i * 8];
}

// ---------------------------------------------------------------------------
// LayerNorm over rows of 1024, fp32 in -> bf16 out.  One block per row.
// ---------------------------------------------------------------------------
__global__ __launch_bounds__(256) void ln_k(const float* __restrict__ x,
                                            const float* __restrict__ w,
                                            const float* __restrict__ b,
                                            __bf16* __restrict__ out) {
  int row = blockIdx.x;
  int tid = threadIdx.x;
  f32x4 v = *(const f32x4*)(x + (size_t)row * 1024 + tid * 4);
  float s = v[0] + v[1] + v[2] + v[3];
  float sq = v[0] * v[0] + v[1] * v[1] + v[2] * v[2] + v[3] * v[3];
#pragma unroll
  for (int m = 1; m < 64; m <<= 1) { s += __shfl_xor(s, m); sq += __shfl_xor(sq, m); }
  __shared__ float rs[4], rq[4];
  int wave = tid >> 6, lane = tid & 63;
  if (lane == 0) { rs[wave] = s; rq[wave] = sq; }
  __syncthreads();
  s  = rs[0] + rs[1] + rs[2] + rs[3];
  sq = rq[0] + rq[1] + rq[2] + rq[3];
  float mu   = s * (1.f / 1024.f);
  float var  = sq * (1.f / 1024.f) - mu * mu;
  float rstd = rsqrtf(var + 1e-5f);
  f32x4 wv = *(const f32x4*)(w + tid * 4);
  f32x4 bv = *(const f32x4*)(b + tid * 4);
  bf16_4 o;
#pragma unroll
  for (int i = 0; i < 4; ++i) o[i] = (__bf16)((v[i] - mu) * rstd * wv[i] + bv[i]);
  *(bf16_4*)(out + (size_t)row * 1024 + tid * 4) = o;
}

// ---------------------------------------------------------------------------
// bf16 GEMM: C[M][N] = A[M][K] @ Bt^T, Bt[N][K].  Tile BM x BN x BK, 4 waves
// in 2x2.  Double-buffered LDS, single barrier per K-iter, XOR chunk swizzle
// (global-address side).  (round-5 verified)
// MODE 0: QKV fused via blockIdx.y; chunk 0 (Q) scaled by QSCALE, chunk 1 (K)
//         row-major bf16, chunk 2 writes V^T [(b*16+h)*64+d][2048 tokens]
// MODE 1: bf16 out, +bias, ReLU
// MODE 2: f32  out, +bias, +f32 residual
// ---------------------------------------------------------------------------
template <int MODE, int BM, int BN, int BK>
__global__ __launch_bounds__(256) void gemm_k(
    const __bf16* __restrict__ A,
    const __bf16* __restrict__ B0, const __bf16* __restrict__ B1,
    const __bf16* __restrict__ B2,
    __bf16* __restrict__ O0, __bf16* __restrict__ O1, __bf16* __restrict__ O2,
    float* __restrict__ Of,
    const float* __restrict__ bias, const float* __restrict__ res,
    int K, int Nchunk, int nBlkM, int nBlkN) {
  constexpr int NC = BK / 8;          // 16B chunks per LDS row
  constexpr int MT = BM / 32, NT = BN / 32;
  constexpr int KK = BK / 32;
  constexpr int RPC = 64 / NC;        // rows covered by one gld_lds16 call
  constexpr int CA = BM / RPC / 4;    // A-calls per wave
  constexpr int CB = BN / RPC / 4;    // B-calls per wave
  __shared__ __align__(16) __bf16 As[2][BM * BK];
  __shared__ __align__(16) __bf16 Bs[2][BN * BK];
  int chunk = blockIdx.y;
  const __bf16* Bt = chunk == 0 ? B0 : (chunk == 1 ? B1 : B2);
  __bf16* Ob       = chunk == 0 ? O0 : (chunk == 1 ? O1 : O2);
  int pid = blockIdx.x;
  const int GM = 8;
  int perG = GM * nBlkN;
  int gid = pid / perG;
  int fm = gid * GM;
  int gsz = min(nBlkM - fm, GM);
  int bm = fm + (pid % gsz);
  int bn = (pid % perG) / gsz;
  int m0 = bm * BM, n0 = bn * BN;
  int tid = threadIdx.x, wave = tid >> 6, lane = tid & 63;
  int quad = lane >> 4, l16 = lane & 15;
  int wm = (wave & 1) * (BM / 2), wn = (wave >> 1) * (BN / 2);
  int srow = lane / NC, schunk = lane % NC;

  f32x4 z = {0.f, 0.f, 0.f, 0.f};
  f32x4 acc[MT][NT];
#pragma unroll
  for (int mt = 0; mt < MT; ++mt)
#pragma unroll
    for (int nt = 0; nt < NT; ++nt) acc[mt][nt] = z;

  const __bf16* Ag = A  + (size_t)m0 * K;
  const __bf16* Bg = Bt + (size_t)n0 * K;

  auto stage = [&](int k0, int buf) {
#pragma unroll
    for (int i = 0; i < CA; ++i) {
      int r0 = (wave * CA + i) * RPC;
      int gc = schunk ^ ((r0 + srow) & (NC - 1));
      gld_lds16(Ag + (size_t)(r0 + srow) * K + k0 + gc * 8, &As[buf][r0 * BK]);
    }
#pragma unroll
    for (int i = 0; i < CB; ++i) {
      int r0 = (wave * CB + i) * RPC;
      int gc = schunk ^ ((r0 + srow) & (NC - 1));
      gld_lds16(Bg + (size_t)(r0 + srow) * K + k0 + gc * 8, &Bs[buf][r0 * BK]);
    }
  };

  auto compute = [&](int buf) {
#pragma unroll
    for (int kk = 0; kk < KK; ++kk) {
      bf16_8 af[MT], bfr[NT];
#pragma unroll
      for (int t = 0; t < MT; ++t) {
        int r = wm + t * 16 + l16;
        int lc = (kk * 4 + quad) ^ (r & (NC - 1));
        af[t] = *(const bf16_8*)(&As[buf][r * BK + lc * 8]);
      }
#pragma unroll
      for (int t = 0; t < NT; ++t) {
        int r = wn + t * 16 + l16;
        int lc = (kk * 4 + quad) ^ (r & (NC - 1));
        bfr[t] = *(const bf16_8*)(&Bs[buf][r * BK + lc * 8]);
      }
#pragma unroll
      for (int mt = 0; mt < MT; ++mt)
#pragma unroll
        for (int nt = 0; nt < NT; ++nt)
          acc[mt][nt] = __builtin_amdgcn_mfma_f32_16x16x32_bf16(af[mt], bfr[nt],
                                                                acc[mt][nt], 0, 0, 0);
    }
  };

  int niter = K / BK;
  stage(0, 0);
  __syncthreads();
  for (int it = 0; it < niter - 1; ++it) {
    stage((it + 1) * BK, (it + 1) & 1);  // async prefetch, overlaps compute
    compute(it & 1);
    __syncthreads();                     // drains prefetch + fences buf reuse
  }
  compute((niter - 1) & 1);

  if (MODE == 0 && chunk == 2) {
#pragma unroll
    for (int mt = 0; mt < MT; ++mt) {
      int mbase = m0 + wm + mt * 16 + quad * 4;
      int bb = mbase >> 11, tt = mbase & 2047;
#pragma unroll
      for (int nt = 0; nt < NT; ++nt) {
        int n = n0 + wn + nt * 16 + l16;
        bf16_4 pk;
#pragma unroll
        for (int r = 0; r < 4; ++r) pk[r] = (__bf16)acc[mt][nt][r];
        *(bf16_4*)(O2 + ((size_t)((bb * 16 + (n >> 6)) * 64 + (n & 63))) * 2048 + tt) = pk;
      }
    }
    return;
  }

  float oscale = (MODE == 0 && chunk == 0) ? QSCALE : 1.0f;
#pragma unroll
  for (int mt = 0; mt < MT; ++mt) {
#pragma unroll
    for (int r = 0; r < 4; ++r) {
      int m = m0 + wm + mt * 16 + quad * 4 + r;
      size_t rowo = (size_t)m * Nchunk;
#pragma unroll
      for (int nt = 0; nt < NT; ++nt) {
        int n = n0 + wn + nt * 16 + l16;
        float v = acc[mt][nt][r];
        if (MODE == 0) {
          Ob[rowo + n] = (__bf16)(v * oscale);
        } else if (MODE == 1) {
          v += bias[n]; v = v > 0.f ? v : 0.f;
          Ob[rowo + n] = (__bf16)v;
        } else {
          v += bias[n] + res[rowo + n];
          Of[rowo + n] = v;
        }
      }
    }
  }
}

// ---------------------------------------------------------------------------
// Flash attention, causal, S^T/O^T, fixed-max softmax.
// Round-11: 512-thread pair-block = 2 waves/SIMD over one shared K/V stream.
//   Round-5 post-mortem: at 1 block/CU = 1 wave/SIMD, per-tile wall was
//   4.1k cy vs ~1.2k cy of work -- every dependent stall (ds_read->MFMA,
//   P roundtrip, barrier drain) fully exposed (VALUBusy 24%).
//   This round keeps the verified per-tile code and block-level balance, but
//   puts BOTH q-tiles of the pair (qtA=15-j, qtB=j) in ONE 512-thread block:
//   - waves 0-3 own qtA's 128 rows, waves 4-7 own qtB's 128 rows.
//   - qtB's kv range [0, 2(j+1)) is a subset of qtA's [0, 2(16-j)) -> one
//     shared staged K/V stream of nT = 2(16-j) tiles; K/V staged ONCE per
//     pair (was twice), each of 8 waves stages 8 rows K + 8 rows V per tile.
//   - per SIMD: one heavy wave (~2qtA+1 tiles) + one light wave (~2qtB+1)
//     ~= 34 wave-tiles, uniform across SIMDs AND blocks; the second wave's
//     compute fills the first wave's stall cycles (the TLP rounds 1-4 kept
//     failing to deliver, now without spill or serial-chain regression).
//   - 256 blocks = 1/CU (grid == CU count), LDS 69.6 KB.
//   Per-wave: 32 q-rows as two 16-col groups sharing K/V LDS fragment loads
//   (round-0 layout, verified).  Waves skip fully-masked tiles (stage always).
// ---------------------------------------------------------------------------
__global__ __launch_bounds__(512) void attn_k(const __bf16* __restrict__ Q,
                                              const __bf16* __restrict__ K,
                                              const __bf16* __restrict__ Vt,
                                              __bf16* __restrict__ O) {
  __shared__ __align__(16) __bf16 Kls[2][64 * 64];
  __shared__ __align__(16) __bf16 Vls[2][64 * 64];
  __shared__ __align__(16) __bf16 Pls[8][32 * 72];

  int i = blockIdx.x;
  int bh = i & 31, j = i >> 5;           // j = pair index 0..7
  int h = bh & 15, b = bh >> 4;
  int qtA = 15 - j, qtB = j;
  int nT = 2 * (qtA + 1);                // staged tiles (covers both q-tiles)
  int tid = threadIdx.x, wave = tid >> 6, lane = tid & 63;
  int quad = lane >> 4, l16 = lane & 15;
  int r8 = lane >> 3, c8 = lane & 7;
  int cswz = c8 ^ r8;                    // staging chunk swizzle
  int so0 = (quad ^ (l16 & 7)) * 8;      // frag chunk offset
  int so1 = so0 ^ 32;
  int qt = wave < 4 ? qtA : qtB;
  int qw = qt * 128 + (wave & 3) * 32;   // this wave's 32 rows

  const __bf16* Kb = K + (size_t)(b * 2048) * 1024 + h * 64;
  const __bf16* Vh = Vt + (size_t)((b * 16 + h) * 64) * 2048;
  __bf16* Pw = &Pls[wave][0];

  f32x4 z = {0.f, 0.f, 0.f, 0.f};
  bf16_8 qf[2][2];
  f32x4 ot[2][4];
  float l_acc[2] = {0.f, 0.f};

#pragma unroll
  for (int g = 0; g < 2; ++g) {
    const __bf16* Qg = Q + ((size_t)(b * 2048 + qw + g * 16 + l16)) * 1024 + h * 64;
    qf[g][0] = *(const bf16_8*)(Qg + quad * 8);
    qf[g][1] = *(const bf16_8*)(Qg + 32 + quad * 8);
#pragma unroll
    for (int dt = 0; dt < 4; ++dt) ot[g][dt] = z;
  }

  // each of 8 waves stages 8 rows of K and 8 rows of V (XOR chunk swizzle
  // on the global side; LDS row base = wave*8, row&7 = r8)
  auto stage = [&](int kt, int buf) {
    int rl = wave * 8 + r8;
    gld_lds16(Kb + (size_t)(kt + rl) * 1024 + cswz * 8, &Kls[buf][(wave * 8) * 64]);
    gld_lds16(Vh + (size_t)rl * 2048 + kt + cswz * 8, &Vls[buf][(wave * 8) * 64]);
  };

  stage(0, 0);
  __syncthreads();
  for (int t = 0; t < nT; ++t) {
    int kt = t * 64;
    int buf = t & 1;
    if (t + 1 < nT) stage((t + 1) * 64, buf ^ 1);  // async prefetch
    if (kt <= qw + 31) {                 // wave-uniform: skip fully-masked
      bool masked = (kt + 63 > qw);
      // --- S^T = K.Q^T, both q-groups share K fragments ---
      f32x4 sf[2][4];
#pragma unroll
      for (int kk = 0; kk < 4; ++kk) {
        const __bf16* kr = &Kls[buf][(kk * 16 + l16) * 64];
        bf16_8 ka = *(const bf16_8*)(kr + so0);
        bf16_8 kb = *(const bf16_8*)(kr + so1);
#pragma unroll
        for (int g = 0; g < 2; ++g) {
          f32x4 a = z;
          a = __builtin_amdgcn_mfma_f32_16x16x32_bf16(ka, qf[g][0], a, 0, 0, 0);
          a = __builtin_amdgcn_mfma_f32_16x16x32_bf16(kb, qf[g][1], a, 0, 0, 0);
          sf[g][kk] = a;
        }
      }
      // --- softmax (fixed max), P -> LDS ---
#pragma unroll
      for (int g = 0; g < 2; ++g) {
        int qrow = qw + g * 16 + l16;
#pragma unroll
        for (int kk = 0; kk < 4; ++kk) {
          bf16_4 pk;
#pragma unroll
          for (int r = 0; r < 4; ++r) {
            float x = sf[g][kk][r];
            if (masked && (kt + kk * 16 + quad * 4 + r > qrow)) x = -1e30f;
            float p = __builtin_amdgcn_exp2f(x);
            l_acc[g] += p;
            pk[r] = (__bf16)p;
          }
          *(bf16_4*)(Pw + (g * 16 + l16) * 72 + kk * 16 + quad * 4) = pk;
        }
      }
      // --- O^T += V^T.P^T, both q-groups share V fragments ---
      bf16_8 pf[2][2];
#pragma unroll
      for (int g = 0; g < 2; ++g) {
        pf[g][0] = *(const bf16_8*)(Pw + (g * 16 + l16) * 72 + quad * 8);
        pf[g][1] = *(const bf16_8*)(Pw + (g * 16 + l16) * 72 + 32 + quad * 8);
      }
#pragma unroll
      for (int dt = 0; dt < 4; ++dt) {
        const __bf16* vr = &Vls[buf][(dt * 16 + l16) * 64];
        bf16_8 v0 = *(const bf16_8*)(vr + so0);
        bf16_8 v1 = *(const bf16_8*)(vr + so1);
#pragma unroll
        for (int g = 0; g < 2; ++g) {
          ot[g][dt] = __builtin_amdgcn_mfma_f32_16x16x32_bf16(v0, pf[g][0], ot[g][dt], 0, 0, 0);
          ot[g][dt] = __builtin_amdgcn_mfma_f32_16x16x32_bf16(v1, pf[g][1], ot[g][dt], 0, 0, 0);
        }
      }
    }
    __syncthreads();                     // drains prefetch + fences buf reuse
  }

#pragma unroll
  for (int g = 0; g < 2; ++g) {
    float l = l_acc[g];
    l += __shfl_xor(l, 16);
    l += __shfl_xor(l, 32);
    float inv = 1.0f / l;
    size_t base = (size_t)(b * 2048 + qw + g * 16 + l16) * 1024 + h * 64;
#pragma unroll
    for (int dt = 0; dt < 4; ++dt) {
      bf16_4 ok;
#pragma unroll
      for (int r = 0; r < 4; ++r) ok[r] = (__bf16)(ot[g][dt][r] * inv);
      *(bf16_4*)(O + base + dt * 16 + quad * 4) = ok;
    }
  }
}

// ---------------------------------------------------------------------------
extern "C" void kernel_launch(void* const* d_in, const int* in_sizes, int n_in,
                              void* d_out, int out_size, void* d_ws,
                              size_t ws_size, hipStream_t stream) {
  const float* x   = (const float*)d_in[0];
  const float* Wq  = (const float*)d_in[1];
  const float* Wk  = (const float*)d_in[2];
  const float* Wv  = (const float*)d_in[3];
  const float* Wp  = (const float*)d_in[4];
  const float* bp  = (const float*)d_in[5];
  const float* W1  = (const float*)d_in[6];
  const float* b1  = (const float*)d_in[7];
  const float* W2  = (const float*)d_in[8];
  const float* b2  = (const float*)d_in[9];
  const float* l1w = (const float*)d_in[10];
  const float* l1b = (const float*)d_in[11];
  const float* l2w = (const float*)d_in[12];
  const float* l2b = (const float*)d_in[13];
  float* out = (float*)d_out;
  char* ws = (char*)d_ws;
  const size_t MB = 1024ull * 1024ull;
  __bf16* WqT = (__bf16*)(ws + 0 * MB);   // 2 MB  [1024][1024]
  __bf16* WkT = (__bf16*)(ws + 2 * MB);   // 2 MB
  __bf16* WvT = (__bf16*)(ws + 4 * MB);   // 2 MB
  __bf16* WpT = (__bf16*)(ws + 6 * MB);   // 2 MB
  __bf16* W1T = (__bf16*)(ws + 8 * MB);   // 8 MB  [4096][1024]
  __bf16* W2T = (__bf16*)(ws + 16 * MB);  // 8 MB  [1024][4096]
  __bf16* hb  = (__bf16*)(ws + 24 * MB);  // 8 MB  LN out (reused for LN2)
  __bf16* Qb  = (__bf16*)(ws + 32 * MB);  // 8 MB  Q (pre-scaled by QSCALE)
  __bf16* Kb_ = (__bf16*)(ws + 40 * MB);  // 8 MB
  __bf16* Vt  = (__bf16*)(ws + 48 * MB);  // 8 MB  V^T [b*16+h][64][2048]
  __bf16* Ab  = (__bf16*)(ws + 56 * MB);  // 8 MB  attention out
  __bf16* F1  = (__bf16*)(ws + 64 * MB);  // 32 MB FFN hidden

  convt_k<<<12288, 256, 0, stream>>>(Wq, Wk, Wv, Wp, W1, W2,
                                     WqT, WkT, WvT, WpT, W1T, W2T);
  ln_k<<<4096, 256, 0, stream>>>(x, l1w, l1b, hb);
  // fused QKV (chunk 0 = Q scaled, chunk 2 writes V^T per head)
  gemm_k<0, 128, 128, 32><<<dim3(256, 3), 256, 0, stream>>>(
      hb, WqT, WkT, WvT, Qb, Kb_, Vt, nullptr, nullptr, nullptr,
      1024, 1024, 32, 8);
  attn_k<<<256, 512, 0, stream>>>(Qb, Kb_, Vt, Ab);
  // x1 = x + attn @ Wproj + bproj (fp32, into d_out); 64x64x64 tiles, 4 blk/CU
  gemm_k<2, 64, 64, 64><<<dim3(1024, 1), 256, 0, stream>>>(
      Ab, WpT, WpT, WpT, nullptr, nullptr, nullptr, out, bp, x,
      1024, 1024, 64, 16);
  ln_k<<<4096, 256, 0, stream>>>(out, l2w, l2b, hb);
  // ff1 = relu(h2 @ W1 + b1)
  gemm_k<1, 128, 128, 32><<<dim3(1024, 1), 256, 0, stream>>>(
      hb, W1T, W1T, W1T, F1, F1, F1, nullptr, b1, nullptr,
      1024, 4096, 32, 32);
  // out = x1 + ff1 @ W2 + b2 ; 64x64x64 tiles, 4 blk/CU
  gemm_k<2, 64, 64, 64><<<dim3(1024, 1), 256, 0, stream>>>(
      F1, W2T, W2T, W2T, nullptr, nullptr, nullptr, out, b2, out,
      4096, 1024, 64, 16);
}

// Round 7
// 334.148 us; speedup vs baseline: 1.1317x; 1.0132x over previous
//
#include <hip/hip_runtime.h>
#include <cstdint>

typedef __attribute__((ext_vector_type(8))) __bf16 bf16_8;
typedef __attribute__((ext_vector_type(4))) __bf16 bf16_4;
typedef __attribute__((ext_vector_type(4))) float f32x4;

// softmax scale folded into Q:  exp(s/32) = exp2(s * log2(e)/32)
#define QSCALE 0.045084220027780106f

// ---------------------------------------------------------------------------
// async global->LDS, 16B per lane. LDS dest = wave-uniform base + lane*16.
// ---------------------------------------------------------------------------
__device__ __forceinline__ void gld_lds16(const __bf16* g, __bf16* l) {
  __builtin_amdgcn_global_load_lds(
      (const __attribute__((address_space(1))) void*)(void*)g,
      (__attribute__((address_space(3))) void*)l, 16, 0, 0);
}

// ---------------------------------------------------------------------------
// Fused weight transpose + f32->bf16 convert.  W[K][N] -> Wt[N][K] bf16.
// ---------------------------------------------------------------------------
__global__ __launch_bounds__(256) void convt_k(
    const float* __restrict__ Wq, const float* __restrict__ Wk,
    const float* __restrict__ Wv, const float* __restrict__ Wp,
    const float* __restrict__ W1, const float* __restrict__ W2,
    __bf16* __restrict__ WqT, __bf16* __restrict__ WkT,
    __bf16* __restrict__ WvT, __bf16* __restrict__ WpT,
    __bf16* __restrict__ W1T, __bf16* __restrict__ W2T) {
  int bid = blockIdx.x;
  const float* in; __bf16* outp; int Kd, Nd, tile;
  if (bid < 4096) {
    int m = bid >> 10; tile = bid & 1023; Kd = 1024; Nd = 1024;
    in   = m == 0 ? Wq  : m == 1 ? Wk  : m == 2 ? Wv  : Wp;
    outp = m == 0 ? WqT : m == 1 ? WkT : m == 2 ? WvT : WpT;
  } else if (bid < 8192) {
    tile = bid - 4096; Kd = 1024; Nd = 4096; in = W1; outp = W1T;
  } else {
    tile = bid - 8192; Kd = 4096; Nd = 1024; in = W2; outp = W2T;
  }
  int tilesN = Nd >> 5;
  int tk = tile / tilesN, tn = tile % tilesN;
  int k0 = tk * 32, n0 = tn * 32;
  __shared__ float tbuf[32][33];
  int tx = threadIdx.x & 31, ty = threadIdx.x >> 5;  // ty 0..7
#pragma unroll
  for (int i = 0; i < 4; ++i)
    tbuf[ty + i * 8][tx] = in[(size_t)(k0 + ty + i * 8) * Nd + (n0 + tx)];
  __syncthreads();
#pragma unroll
  for (int i = 0; i < 4; ++i)
    outp[(size_t)(n0 + ty + i * 8) * Kd + (k0 + tx)] = (__bf16)tbuf[tx][ty + i * 8];
}

// ---------------------------------------------------------------------------
// LayerNorm over rows of 1024, fp32 in -> bf16 out.  One block per row.
// ---------------------------------------------------------------------------
__global__ __launch_bounds__(256) void ln_k(const float* __restrict__ x,
                                            const float* __restrict__ w,
                                            const float* __restrict__ b,
                                            __bf16* __restrict__ out) {
  int row = blockIdx.x;
  int tid = threadIdx.x;
  f32x4 v = *(const f32x4*)(x + (size_t)row * 1024 + tid * 4);
  float s = v[0] + v[1] + v[2] + v[3];
  float sq = v[0] * v[0] + v[1] * v[1] + v[2] * v[2] + v[3] * v[3];
#pragma unroll
  for (int m = 1; m < 64; m <<= 1) { s += __shfl_xor(s, m); sq += __shfl_xor(sq, m); }
  __shared__ float rs[4], rq[4];
  int wave = tid >> 6, lane = tid & 63;
  if (lane == 0) { rs[wave] = s; rq[wave] = sq; }
  __syncthreads();
  s  = rs[0] + rs[1] + rs[2] + rs[3];
  sq = rq[0] + rq[1] + rq[2] + rq[3];
  float mu   = s * (1.f / 1024.f);
  float var  = sq * (1.f / 1024.f) - mu * mu;
  float rstd = rsqrtf(var + 1e-5f);
  f32x4 wv = *(const f32x4*)(w + tid * 4);
  f32x4 bv = *(const f32x4*)(b + tid * 4);
  bf16_4 o;
#pragma unroll
  for (int i = 0; i < 4; ++i) o[i] = (__bf16)((v[i] - mu) * rstd * wv[i] + bv[i]);
  *(bf16_4*)(out + (size_t)row * 1024 + tid * 4) = o;
}

// ---------------------------------------------------------------------------
// bf16 GEMM: C[M][N] = A[M][K] @ Bt^T, Bt[N][K].  Tile BM x BN x BK, 4 waves
// in 2x2.  Double-buffered LDS, single barrier per K-iter, XOR chunk swizzle
// (global-address side).  (round-5 verified)
// MODE 0: QKV fused via blockIdx.y; chunk 0 (Q) scaled by QSCALE, chunk 1 (K)
//         row-major bf16, chunk 2 writes V^T [(b*16+h)*64+d][2048 tokens]
// MODE 1: bf16 out, +bias, ReLU
// MODE 2: f32  out, +bias, +f32 residual
// ---------------------------------------------------------------------------
template <int MODE, int BM, int BN, int BK>
__global__ __launch_bounds__(256) void gemm_k(
    const __bf16* __restrict__ A,
    const __bf16* __restrict__ B0, const __bf16* __restrict__ B1,
    const __bf16* __restrict__ B2,
    __bf16* __restrict__ O0, __bf16* __restrict__ O1, __bf16* __restrict__ O2,
    float* __restrict__ Of,
    const float* __restrict__ bias, const float* __restrict__ res,
    int K, int Nchunk, int nBlkM, int nBlkN) {
  constexpr int NC = BK / 8;          // 16B chunks per LDS row
  constexpr int MT = BM / 32, NT = BN / 32;
  constexpr int KK = BK / 32;
  constexpr int RPC = 64 / NC;        // rows covered by one gld_lds16 call
  constexpr int CA = BM / RPC / 4;    // A-calls per wave
  constexpr int CB = BN / RPC / 4;    // B-calls per wave
  __shared__ __align__(16) __bf16 As[2][BM * BK];
  __shared__ __align__(16) __bf16 Bs[2][BN * BK];
  int chunk = blockIdx.y;
  const __bf16* Bt = chunk == 0 ? B0 : (chunk == 1 ? B1 : B2);
  __bf16* Ob       = chunk == 0 ? O0 : (chunk == 1 ? O1 : O2);
  int pid = blockIdx.x;
  const int GM = 8;
  int perG = GM * nBlkN;
  int gid = pid / perG;
  int fm = gid * GM;
  int gsz = min(nBlkM - fm, GM);
  int bm = fm + (pid % gsz);
  int bn = (pid % perG) / gsz;
  int m0 = bm * BM, n0 = bn * BN;
  int tid = threadIdx.x, wave = tid >> 6, lane = tid & 63;
  int quad = lane >> 4, l16 = lane & 15;
  int wm = (wave & 1) * (BM / 2), wn = (wave >> 1) * (BN / 2);
  int srow = lane / NC, schunk = lane % NC;

  f32x4 z = {0.f, 0.f, 0.f, 0.f};
  f32x4 acc[MT][NT];
#pragma unroll
  for (int mt = 0; mt < MT; ++mt)
#pragma unroll
    for (int nt = 0; nt < NT; ++nt) acc[mt][nt] = z;

  const __bf16* Ag = A  + (size_t)m0 * K;
  const __bf16* Bg = Bt + (size_t)n0 * K;

  auto stage = [&](int k0, int buf) {
#pragma unroll
    for (int i = 0; i < CA; ++i) {
      int r0 = (wave * CA + i) * RPC;
      int gc = schunk ^ ((r0 + srow) & (NC - 1));
      gld_lds16(Ag + (size_t)(r0 + srow) * K + k0 + gc * 8, &As[buf][r0 * BK]);
    }
#pragma unroll
    for (int i = 0; i < CB; ++i) {
      int r0 = (wave * CB + i) * RPC;
      int gc = schunk ^ ((r0 + srow) & (NC - 1));
      gld_lds16(Bg + (size_t)(r0 + srow) * K + k0 + gc * 8, &Bs[buf][r0 * BK]);
    }
  };

  auto compute = [&](int buf) {
#pragma unroll
    for (int kk = 0; kk < KK; ++kk) {
      bf16_8 af[MT], bfr[NT];
#pragma unroll
      for (int t = 0; t < MT; ++t) {
        int r = wm + t * 16 + l16;
        int lc = (kk * 4 + quad) ^ (r & (NC - 1));
        af[t] = *(const bf16_8*)(&As[buf][r * BK + lc * 8]);
      }
#pragma unroll
      for (int t = 0; t < NT; ++t) {
        int r = wn + t * 16 + l16;
        int lc = (kk * 4 + quad) ^ (r & (NC - 1));
        bfr[t] = *(const bf16_8*)(&Bs[buf][r * BK + lc * 8]);
      }
#pragma unroll
      for (int mt = 0; mt < MT; ++mt)
#pragma unroll
        for (int nt = 0; nt < NT; ++nt)
          acc[mt][nt] = __builtin_amdgcn_mfma_f32_16x16x32_bf16(af[mt], bfr[nt],
                                                                acc[mt][nt], 0, 0, 0);
    }
  };

  int niter = K / BK;
  stage(0, 0);
  __syncthreads();
  for (int it = 0; it < niter - 1; ++it) {
    stage((it + 1) * BK, (it + 1) & 1);  // async prefetch, overlaps compute
    compute(it & 1);
    __syncthreads();                     // drains prefetch + fences buf reuse
  }
  compute((niter - 1) & 1);

  if (MODE == 0 && chunk == 2) {
#pragma unroll
    for (int mt = 0; mt < MT; ++mt) {
      int mbase = m0 + wm + mt * 16 + quad * 4;
      int bb = mbase >> 11, tt = mbase & 2047;
#pragma unroll
      for (int nt = 0; nt < NT; ++nt) {
        int n = n0 + wn + nt * 16 + l16;
        bf16_4 pk;
#pragma unroll
        for (int r = 0; r < 4; ++r) pk[r] = (__bf16)acc[mt][nt][r];
        *(bf16_4*)(O2 + ((size_t)((bb * 16 + (n >> 6)) * 64 + (n & 63))) * 2048 + tt) = pk;
      }
    }
    return;
  }

  float oscale = (MODE == 0 && chunk == 0) ? QSCALE : 1.0f;
#pragma unroll
  for (int mt = 0; mt < MT; ++mt) {
#pragma unroll
    for (int r = 0; r < 4; ++r) {
      int m = m0 + wm + mt * 16 + quad * 4 + r;
      size_t rowo = (size_t)m * Nchunk;
#pragma unroll
      for (int nt = 0; nt < NT; ++nt) {
        int n = n0 + wn + nt * 16 + l16;
        float v = acc[mt][nt][r];
        if (MODE == 0) {
          Ob[rowo + n] = (__bf16)(v * oscale);
        } else if (MODE == 1) {
          v += bias[n]; v = v > 0.f ? v : 0.f;
          Ob[rowo + n] = (__bf16)v;
        } else {
          v += bias[n] + res[rowo + n];
          Of[rowo + n] = v;
        }
      }
    }
  }
}

// ---------------------------------------------------------------------------
// Flash attention, causal, S^T/O^T, fixed-max softmax.
// Round-12: round-5 structure (best measured: 58.5us, uniform 34-tile pair
// blocks, 256 blocks = 1/CU) + T3/T4 counted-vmcnt pipeline.
//   Round-5/6 post-mortem: per-tile wall 4.1k cy vs ~1.5k cy of chained
//   work; __syncthreads emits s_waitcnt vmcnt(0) which DRAINS the prefetch
//   issued one line earlier -> a full L2/HBM round trip on the critical
//   path every tile.  Round-6's heavy+light wave pairing failed because the
//   light wave's tiles are a prefix (idle in later iterations; j=0 block
//   degenerates to 1 active wave x 32 iterations).
//   This round: 3-deep LDS ring + raw s_barrier + counted vmcnt:
//     prologue: stage(0,b0), stage(1,b1)
//     iter t:   s_waitcnt vmcnt(4)   [own oldest 4 staging ops = tile t done;
//                                     tile t+1's 4 stay in flight ACROSS the
//                                     barrier; last iter: vmcnt(0)]
//               s_barrier            [all waves' tile-t stages done; also
//                                     fences buf reuse: everyone finished
//                                     computing t-1 before stage(t+2) writes]
//               stage(t+2, (t+2)%3)  [prefetch has ~2 tile-computes to land]
//               compute(t, t%3)
//   Each wave issues exactly 4 gld_lds16 per stage -> own-vmcnt counting is
//   uniform across waves.  Phase boundary (writeO stores + loadQ loads) adds
//   transient vmcnt ops -> one-iteration over-wait, accepted.
//   Per-wave: 32 q-rows as two 16-col groups sharing K/V LDS fragment loads
//   (round-0 layout, verified).  Waves skip fully-masked tiles (stage+sync
//   always, wave-uniform).
// ---------------------------------------------------------------------------
__global__ __launch_bounds__(256) void attn_k(const __bf16* __restrict__ Q,
                                              const __bf16* __restrict__ K,
                                              const __bf16* __restrict__ Vt,
                                              __bf16* __restrict__ O) {
  __shared__ __align__(16) __bf16 Kls[3][64 * 64];
  __shared__ __align__(16) __bf16 Vls[3][64 * 64];
  __shared__ __align__(16) __bf16 Pls[4][32 * 72];

  int i = blockIdx.x;
  int bh = i & 31, j = i >> 5;           // j = pair index 0..7
  int h = bh & 15, b = bh >> 4;
  int qtA = 15 - j, qtB = j;             // heavy phase first
  int nA = 2 * (qtA + 1);
  int nT = 34;                           // nA + nB, always 34
  int tid = threadIdx.x, wave = tid >> 6, lane = tid & 63;
  int quad = lane >> 4, l16 = lane & 15;
  int r8 = lane >> 3, c8 = lane & 7;
  int cswz = c8 ^ r8;                    // staging chunk swizzle
  int so0 = (quad ^ (l16 & 7)) * 8;      // frag chunk offset
  int so1 = so0 ^ 32;

  const __bf16* Kb = K + (size_t)(b * 2048) * 1024 + h * 64;
  const __bf16* Vh = Vt + (size_t)((b * 16 + h) * 64) * 2048;
  __bf16* Pw = &Pls[wave][0];

  f32x4 z = {0.f, 0.f, 0.f, 0.f};
  bf16_8 qf[2][2];
  f32x4 ot[2][4];
  float l_acc[2] = {0.f, 0.f};
  int qw = qtA * 128 + wave * 32;        // this wave's rows in current phase

  auto loadQ = [&](int qt) {
    qw = qt * 128 + wave * 32;
#pragma unroll
    for (int g = 0; g < 2; ++g) {
      const __bf16* Qg = Q + ((size_t)(b * 2048 + qw + g * 16 + l16)) * 1024 + h * 64;
      qf[g][0] = *(const bf16_8*)(Qg + quad * 8);
      qf[g][1] = *(const bf16_8*)(Qg + 32 + quad * 8);
    }
#pragma unroll
    for (int g = 0; g < 2; ++g) {
#pragma unroll
      for (int dt = 0; dt < 4; ++dt) ot[g][dt] = z;
      l_acc[g] = 0.f;
    }
  };

  auto stage = [&](int kt, int buf) {
#pragma unroll
    for (int i2 = 0; i2 < 2; ++i2) {
      int rl = wave * 16 + i2 * 8 + r8;
      gld_lds16(Kb + (size_t)(kt + rl) * 1024 + cswz * 8,
                &Kls[buf][(wave * 16 + i2 * 8) * 64]);
      gld_lds16(Vh + (size_t)rl * 2048 + kt + cswz * 8,
                &Vls[buf][(wave * 16 + i2 * 8) * 64]);
    }
  };

  auto writeO = [&]() {
#pragma unroll
    for (int g = 0; g < 2; ++g) {
      float l = l_acc[g];
      l += __shfl_xor(l, 16);
      l += __shfl_xor(l, 32);
      float inv = 1.0f / l;
      size_t base = (size_t)(b * 2048 + qw + g * 16 + l16) * 1024 + h * 64;
#pragma unroll
      for (int dt = 0; dt < 4; ++dt) {
        bf16_4 ok;
#pragma unroll
        for (int r = 0; r < 4; ++r) ok[r] = (__bf16)(ot[g][dt][r] * inv);
        *(bf16_4*)(O + base + dt * 16 + quad * 4) = ok;
      }
    }
  };

  auto ktOf = [&](int t) { return (t < nA ? t : t - nA) * 64; };

  loadQ(qtA);
  stage(ktOf(0), 0);
  stage(ktOf(1), 1);
  for (int t = 0; t < nT; ++t) {
    int kt = ktOf(t);
    int buf = t % 3;
    // --- T4: counted wait (tile t's 4 staging ops done; tile t+1's stay
    //     in flight across the barrier).  Last iter drains fully. ---
    if (t < nT - 1) asm volatile("s_waitcnt vmcnt(4)" ::: "memory");
    else            asm volatile("s_waitcnt vmcnt(0)" ::: "memory");
    __builtin_amdgcn_s_barrier();        // tile-t staged + buf-reuse fence
    if (t + 2 < nT) stage(ktOf(t + 2), (t + 2) % 3);  // issue-early prefetch
    if (t == nA) {                       // phase boundary (wave-uniform)
      writeO();
      loadQ(qtB);
    }
    if (kt <= qw + 31) {                 // wave-uniform: skip fully-masked
      bool masked = (kt + 63 > qw);
      // --- S^T = K.Q^T, both q-groups share K fragments ---
      f32x4 sf[2][4];
#pragma unroll
      for (int kk = 0; kk < 4; ++kk) {
        const __bf16* kr = &Kls[buf][(kk * 16 + l16) * 64];
        bf16_8 ka = *(const bf16_8*)(kr + so0);
        bf16_8 kb = *(const bf16_8*)(kr + so1);
#pragma unroll
        for (int g = 0; g < 2; ++g) {
          f32x4 a = z;
          a = __builtin_amdgcn_mfma_f32_16x16x32_bf16(ka, qf[g][0], a, 0, 0, 0);
          a = __builtin_amdgcn_mfma_f32_16x16x32_bf16(kb, qf[g][1], a, 0, 0, 0);
          sf[g][kk] = a;
        }
      }
      // --- softmax (fixed max), P -> LDS ---
#pragma unroll
      for (int g = 0; g < 2; ++g) {
        int qrow = qw + g * 16 + l16;
#pragma unroll
        for (int kk = 0; kk < 4; ++kk) {
          bf16_4 pk;
#pragma unroll
          for (int r = 0; r < 4; ++r) {
            float x = sf[g][kk][r];
            if (masked && (kt + kk * 16 + quad * 4 + r > qrow)) x = -1e30f;
            float p = __builtin_amdgcn_exp2f(x);
            l_acc[g] += p;
            pk[r] = (__bf16)p;
          }
          *(bf16_4*)(Pw + (g * 16 + l16) * 72 + kk * 16 + quad * 4) = pk;
        }
      }
      // --- O^T += V^T.P^T, both q-groups share V fragments ---
      bf16_8 pf[2][2];
#pragma unroll
      for (int g = 0; g < 2; ++g) {
        pf[g][0] = *(const bf16_8*)(Pw + (g * 16 + l16) * 72 + quad * 8);
        pf[g][1] = *(const bf16_8*)(Pw + (g * 16 + l16) * 72 + 32 + quad * 8);
      }
#pragma unroll
      for (int dt = 0; dt < 4; ++dt) {
        const __bf16* vr = &Vls[buf][(dt * 16 + l16) * 64];
        bf16_8 v0 = *(const bf16_8*)(vr + so0);
        bf16_8 v1 = *(const bf16_8*)(vr + so1);
#pragma unroll
        for (int g = 0; g < 2; ++g) {
          ot[g][dt] = __builtin_amdgcn_mfma_f32_16x16x32_bf16(v0, pf[g][0], ot[g][dt], 0, 0, 0);
          ot[g][dt] = __builtin_amdgcn_mfma_f32_16x16x32_bf16(v1, pf[g][1], ot[g][dt], 0, 0, 0);
        }
      }
    }
  }
  writeO();                              // phase B output
}

// ---------------------------------------------------------------------------
extern "C" void kernel_launch(void* const* d_in, const int* in_sizes, int n_in,
                              void* d_out, int out_size, void* d_ws,
                              size_t ws_size, hipStream_t stream) {
  const float* x   = (const float*)d_in[0];
  const float* Wq  = (const float*)d_in[1];
  const float* Wk  = (const float*)d_in[2];
  const float* Wv  = (const float*)d_in[3];
  const float* Wp  = (const float*)d_in[4];
  const float* bp  = (const float*)d_in[5];
  const float* W1  = (const float*)d_in[6];
  const float* b1  = (const float*)d_in[7];
  const float* W2  = (const float*)d_in[8];
  const float* b2  = (const float*)d_in[9];
  const float* l1w = (const float*)d_in[10];
  const float* l1b = (const float*)d_in[11];
  const float* l2w = (const float*)d_in[12];
  const float* l2b = (const float*)d_in[13];
  float* out = (float*)d_out;
  char* ws = (char*)d_ws;
  const size_t MB = 1024ull * 1024ull;
  __bf16* WqT = (__bf16*)(ws + 0 * MB);   // 2 MB  [1024][1024]
  __bf16* WkT = (__bf16*)(ws + 2 * MB);   // 2 MB
  __bf16* WvT = (__bf16*)(ws + 4 * MB);   // 2 MB
  __bf16* WpT = (__bf16*)(ws + 6 * MB);   // 2 MB
  __bf16* W1T = (__bf16*)(ws + 8 * MB);   // 8 MB  [4096][1024]
  __bf16* W2T = (__bf16*)(ws + 16 * MB);  // 8 MB  [1024][4096]
  __bf16* hb  = (__bf16*)(ws + 24 * MB);  // 8 MB  LN out (reused for LN2)
  __bf16* Qb  = (__bf16*)(ws + 32 * MB);  // 8 MB  Q (pre-scaled by QSCALE)
  __bf16* Kb_ = (__bf16*)(ws + 40 * MB);  // 8 MB
  __bf16* Vt  = (__bf16*)(ws + 48 * MB);  // 8 MB  V^T [b*16+h][64][2048]
  __bf16* Ab  = (__bf16*)(ws + 56 * MB);  // 8 MB  attention out
  __bf16* F1  = (__bf16*)(ws + 64 * MB);  // 32 MB FFN hidden

  convt_k<<<12288, 256, 0, stream>>>(Wq, Wk, Wv, Wp, W1, W2,
                                     WqT, WkT, WvT, WpT, W1T, W2T);
  ln_k<<<4096, 256, 0, stream>>>(x, l1w, l1b, hb);
  // fused QKV (chunk 0 = Q scaled, chunk 2 writes V^T per head)
  gemm_k<0, 128, 128, 32><<<dim3(256, 3), 256, 0, stream>>>(
      hb, WqT, WkT, WvT, Qb, Kb_, Vt, nullptr, nullptr, nullptr,
      1024, 1024, 32, 8);
  attn_k<<<256, 256, 0, stream>>>(Qb, Kb_, Vt, Ab);
  // x1 = x + attn @ Wproj + bproj (fp32, into d_out); 64x64x64 tiles, 4 blk/CU
  gemm_k<2, 64, 64, 64><<<dim3(1024, 1), 256, 0, stream>>>(
      Ab, WpT, WpT, WpT, nullptr, nullptr, nullptr, out, bp, x,
      1024, 1024, 64, 16);
  ln_k<<<4096, 256, 0, stream>>>(out, l2w, l2b, hb);
  // ff1 = relu(h2 @ W1 + b1)
  gemm_k<1, 128, 128, 32><<<dim3(1024, 1), 256, 0, stream>>>(
      hb, W1T, W1T, W1T, F1, F1, F1, nullptr, b1, nullptr,
      1024, 4096, 32, 32);
  // out = x1 + ff1 @ W2 + b2 ; 64x64x64 tiles, 4 blk/CU
  gemm_k<2, 64, 64, 64><<<dim3(1024, 1), 256, 0, stream>>>(
      F1, W2T, W2T, W2T, nullptr, nullptr, nullptr, out, b2, out,
      4096, 1024, 64, 16);
}